// Round 11
// baseline (1037.563 us; speedup 1.0000x reference)
//
#include <hip/hip_runtime.h>
#include <stdint.h>

#define N_USER_C  50000
#define N_ITEM_C  100000
#define N_NODES_C 150000
#define EMB_C     64
#define NNZ_C     1200000
#define BATCH_C   4096

#define BKT_SHIFT 8                                   // 256 rows per bucket
#define BKT_ROWS  256
#define NB        ((N_NODES_C + BKT_ROWS - 1) / BKT_ROWS)   // 586
#define NSL       10                                  // column slices (col>>14)
#define SL_SHIFT  14
#define NKS       (NB * NSL)                          // 5860 (bucket,slice) keys
#define CH        16384                               // edges per binning block
#define NBLK      ((NNZ_C + CH - 1) / CH)             // 74
#define N2X       (NKS * NBLK)                        // 433640
#define SCH       4096                                // scan chunk
#define SBLK      ((N2X + SCH - 1) / SCH)             // 106
#define COL_MASK  0x3FFFF                             // 18 bits

#define SPMM_B    37500                               // row-wave blocks (hop3)
#define GB        3072                                // 786432 threads / 256
#define THB       2048                                // tohalf stride blocks
#define FB        3072                                // flag-seed blocks

typedef _Float16 h16;
typedef _Float16 h16x4 __attribute__((ext_vector_type(4)));

// ---------------- pass A: per-(block,bucket,slice) histogram + flags3 zero ----------------
__global__ __launch_bounds__(1024) void k_bin_count(const float* __restrict__ du,
                                                    const int* __restrict__ rows,
                                                    const int* __restrict__ cols,
                                                    int* __restrict__ cnt2,
                                                    int* __restrict__ flagz) {
    __shared__ int bk[NKS];                            // 23.4 KB
    int t = threadIdx.x, blk = blockIdx.x;
    for (int i = blk * 1024 + t; i < N_NODES_C; i += NBLK * 1024) flagz[i] = 0;
    for (int i = t; i < NKS; i += 1024) bk[i] = 0;
    __syncthreads();
    int base = blk * CH;
    for (int i = 0; i < CH; i += 1024) {
        int e = base + i + t;
        if (e < NNZ_C && floorf(0.9f + du[e]) != 0.0f) {
            int ks = (rows[e] >> BKT_SHIFT) * NSL + (cols[e] >> SL_SHIFT);
            atomicAdd(&bk[ks], 1);
        }
    }
    __syncthreads();
    for (int i = t; i < NKS; i += 1024) cnt2[i * NBLK + blk] = bk[i];
}

// ---------------- 3-phase flat exclusive scan over N2X counters ----------------
__global__ __launch_bounds__(256) void k_scan_a(const int* __restrict__ cnt2,
                                                int* __restrict__ bsum) {
    __shared__ int red[256];
    int base = blockIdx.x * SCH;
    int s = 0;
    for (int i = threadIdx.x; i < SCH; i += 256) {
        int idx = base + i;
        if (idx < N2X) s += cnt2[idx];
    }
    red[threadIdx.x] = s;
    __syncthreads();
    for (int off = 128; off > 0; off >>= 1) {
        if (threadIdx.x < off) red[threadIdx.x] += red[threadIdx.x + off];
        __syncthreads();
    }
    if (threadIdx.x == 0) bsum[blockIdx.x] = red[0];
}

__global__ __launch_bounds__(128) void k_scan_b(const int* __restrict__ bsum,
                                                int* __restrict__ bpre,
                                                int* __restrict__ base2,
                                                int* __restrict__ row_start) {
    __shared__ int sh[128];
    int t = threadIdx.x;
    int v0 = (t < SBLK) ? bsum[t] : 0;
    sh[t] = v0;
    __syncthreads();
    for (int off = 1; off < 128; off <<= 1) {
        int v = (t >= off) ? sh[t - off] : 0;
        __syncthreads();
        sh[t] += v;
        __syncthreads();
    }
    if (t < SBLK) bpre[t] = sh[t] - v0;
    if (t == 127) {
        base2[N2X] = sh[127];                          // total kept edges
        row_start[N_NODES_C] = sh[127];                // CSR sentinel
    }
}

__global__ __launch_bounds__(256) void k_scan_c(const int* __restrict__ cnt2,
                                                const int* __restrict__ bpre,
                                                int* __restrict__ base2) {
    __shared__ int sh[SCH];                            // 16 KB
    __shared__ int tsum[256];
    int base = blockIdx.x * SCH;
    int t = threadIdx.x;
    for (int i = t; i < SCH; i += 256) {
        int idx = base + i;
        sh[i] = (idx < N2X) ? cnt2[idx] : 0;
    }
    __syncthreads();
    int loc[16];
    int run = 0;
    #pragma unroll
    for (int i = 0; i < 16; ++i) { loc[i] = run; run += sh[t * 16 + i]; }
    tsum[t] = run;
    __syncthreads();
    for (int off = 1; off < 256; off <<= 1) {
        int v = (t >= off) ? tsum[t - off] : 0;
        __syncthreads();
        tsum[t] += v;
        __syncthreads();
    }
    int texcl = tsum[t] - run;
    int boff = bpre[blockIdx.x];
    #pragma unroll
    for (int i = 0; i < 16; ++i) {
        int idx = base + t * 16 + i;
        if (idx < N2X) base2[idx] = boff + texcl + loc[i];
    }
}

// ---------------- pass C: (bucket,slice)-grouped write of packed (rl|col, val) ----------------
__global__ __launch_bounds__(1024) void k_bin_write(const float* __restrict__ av,
                                                    const float* __restrict__ du,
                                                    const int* __restrict__ rows,
                                                    const int* __restrict__ cols,
                                                    const int* __restrict__ base2,
                                                    int2* __restrict__ ev) {
    __shared__ int cur[NKS];                           // 23.4 KB
    int t = threadIdx.x, blk = blockIdx.x;
    for (int i = t; i < NKS; i += 1024) cur[i] = base2[i * NBLK + blk];
    __syncthreads();
    int base = blk * CH;
    for (int i = 0; i < CH; i += 1024) {
        int e = base + i + t;
        if (e < NNZ_C) {
            float m = floorf(0.9f + du[e]);
            if (m != 0.0f) {
                float v = av[e] * m * (float)(1.0 / 0.9);
                int r = rows[e], c = cols[e];
                int ks = (r >> BKT_SHIFT) * NSL + (c >> SL_SHIFT);
                int pos = atomicAdd(&cur[ks], 1);
                int2 p;
                p.x = ((r & (BKT_ROWS - 1)) << 18) | c;   // rl:8 | col:18
                p.y = __float_as_int(v);
                ev[pos] = p;
            }
        }
    }
}

// ---------------- pass D: per-bucket exact row sort -> CSR ep (for hop3/hop4) ----------------
__global__ __launch_bounds__(256) void k_bucket_sort(const int2* __restrict__ ev,
                                                     const int* __restrict__ base2,
                                                     int2* __restrict__ ep,
                                                     int* __restrict__ row_start) {
    __shared__ int rowcnt[BKT_ROWS];
    __shared__ int cursor[BKT_ROWS];
    __shared__ int tsum[256];
    int t = threadIdx.x, k = blockIdx.x;
    int rowBase = k << BKT_SHIFT;
    int bstart = base2[(size_t)k * NSL * NBLK];
    int bend   = base2[(size_t)(k + 1) * NSL * NBLK];  // k=NB-1 hits sentinel
    rowcnt[t] = 0;
    __syncthreads();
    for (int e = bstart + t; e < bend; e += 256)
        atomicAdd(&rowcnt[((unsigned)ev[e].x) >> 18], 1);
    __syncthreads();
    int c = rowcnt[t];
    tsum[t] = c;
    __syncthreads();
    for (int off = 1; off < 256; off <<= 1) {
        int v = (t >= off) ? tsum[t - off] : 0;
        __syncthreads();
        tsum[t] += v;
        __syncthreads();
    }
    int excl = tsum[t] - c;
    cursor[t] = excl;
    int gr = rowBase + t;
    if (gr < N_NODES_C) row_start[gr] = bstart + excl;
    __syncthreads();
    for (int e = bstart + t; e < bend; e += 256) {
        int2 p = ev[e];
        int rl = ((unsigned)p.x) >> 18;
        int slot = atomicAdd(&cursor[rl], 1);
        p.x &= COL_MASK;
        ep[bstart + slot] = p;
    }
}

// ---------------- shared device helpers ----------------
__device__ __forceinline__ void batch_row_a(int wid, int idx0,
                                            const int* __restrict__ users,
                                            const int* __restrict__ pos,
                                            const int* __restrict__ neg,
                                            const int* __restrict__ ua,
                                            const int* __restrict__ pa,
                                            const int* __restrict__ na,
                                            int& row, int& a) {
    int s = wid >> 12;
    int j = wid & (BATCH_C - 1);
    if (s == 0)      { row = users[j] + (idx0 ? N_USER_C : 0); a = ua[j]; }
    else if (s == 1) { row = pos[j]   + (idx0 ? 0 : N_USER_C); a = pa[j]; }
    else             { row = neg[j]   + (idx0 ? 0 : N_USER_C); a = na[j]; }
}

__device__ __forceinline__ void gather_body(const h16* __restrict__ src,
                                            float* __restrict__ out, int t, int hop,
                                            int idx0,
                                            const int* __restrict__ users,
                                            const int* __restrict__ pos,
                                            const int* __restrict__ neg,
                                            const int* __restrict__ ua,
                                            const int* __restrict__ pa,
                                            const int* __restrict__ na) {
    int d = t & 63;
    int b = t >> 6;
    int row, a;
    batch_row_a(b, idx0, users, pos, neg, ua, pa, na, row, a);
    if (hop <= a)
        out[t] += (float)src[(int64_t)row * EMB_C + d] / (float)(a + 1);
}

// slice-blocked LDS-accumulated SpMM body: one block per 256-row bucket
__device__ __forceinline__ void spmm_lds_body(int k, int tid, float* accS,
                                              const int* __restrict__ base2,
                                              const int2* __restrict__ ev,
                                              const h16x4* __restrict__ ego,
                                              h16x4* __restrict__ nxt) {
    float4* a4 = (float4*)accS;
    for (int i = tid; i < BKT_ROWS * 16; i += 256)
        a4[i] = make_float4(0.f, 0.f, 0.f, 0.f);
    __syncthreads();
    int bstart = base2[(size_t)k * NSL * NBLK];
    int bend   = base2[(size_t)(k + 1) * NSL * NBLK];
    int l = tid & 15;                                  // 16 lanes per edge
    #pragma unroll 4
    for (int it = bstart + (tid >> 4); it < bend; it += 16) {
        long long raw = __builtin_nontemporal_load((const long long*)(ev + it));
        int   px = (int)(raw & 0xFFFFFFFFLL);
        float v  = __int_as_float((int)(raw >> 32));
        int rl  = ((unsigned)px) >> 18;
        int col = px & COL_MASK;
        h16x4 g = ego[(int64_t)col * 16 + l];          // slice-ordered -> L2 hit
        float* dst = accS + rl * 64 + l * 4;
        atomicAdd(dst + 0, v * (float)g[0]);
        atomicAdd(dst + 1, v * (float)g[1]);
        atomicAdd(dst + 2, v * (float)g[2]);
        atomicAdd(dst + 3, v * (float)g[3]);
    }
    __syncthreads();
    int rowBase = k << BKT_SHIFT;
    for (int rb = 0; rb < BKT_ROWS; rb += 16) {
        int r  = rb + (tid >> 4);
        int gr = rowBase + r;
        if (gr < N_NODES_C) {
            float4 av = a4[r * 16 + l];
            h16x4 h;
            h[0] = (h16)av.x; h[1] = (h16)av.y; h[2] = (h16)av.z; h[3] = (h16)av.w;
            nxt[(int64_t)gr * 16 + l] = h;
        }
    }
}

// CSR row-wave SpMM body (hop-3, flag-pruned)
__device__ __forceinline__ void spmm_row_body(int wid, int lane,
                                              const int* __restrict__ rs,
                                              const int2* __restrict__ ep,
                                              const h16x4* __restrict__ ego,
                                              h16x4* __restrict__ nxt,
                                              const int* __restrict__ flag) {
    if (wid >= N_NODES_C) return;
    if (flag && flag[wid] == 0) return;
    int start = rs[wid];
    int end   = rs[wid + 1];
    int eo = lane >> 4;
    int l  = lane & 15;
    float4 acc = make_float4(0.f, 0.f, 0.f, 0.f);
    #pragma unroll 2
    for (int it = start + eo; it < end; it += 4) {
        int2 p = ep[it];
        float v = __int_as_float(p.y);
        h16x4 g = ego[(int64_t)p.x * 16 + l];
        acc.x += v * (float)g[0]; acc.y += v * (float)g[1];
        acc.z += v * (float)g[2]; acc.w += v * (float)g[3];
    }
    acc.x += __shfl_xor(acc.x, 16); acc.y += __shfl_xor(acc.y, 16);
    acc.z += __shfl_xor(acc.z, 16); acc.w += __shfl_xor(acc.w, 16);
    acc.x += __shfl_xor(acc.x, 32); acc.y += __shfl_xor(acc.y, 32);
    acc.z += __shfl_xor(acc.z, 32); acc.w += __shfl_xor(acc.w, 32);
    if (lane < 16) {
        h16x4 h;
        h[0] = (h16)acc.x; h[1] = (h16)acc.y; h[2] = (h16)acc.z; h[3] = (h16)acc.w;
        nxt[(int64_t)wid * 16 + l] = h;
    }
}

// ---------------- fused: fp16 conversion + pre-scaled hop-0 init ----------------
__global__ __launch_bounds__(256) void k_prep(const float* __restrict__ ue,
                                              const float* __restrict__ ie,
                                              h16x4* __restrict__ dst,
                                              float* __restrict__ out,
                                              const int* __restrict__ users,
                                              const int* __restrict__ pos,
                                              const int* __restrict__ neg,
                                              const int* __restrict__ ua,
                                              const int* __restrict__ pa,
                                              const int* __restrict__ na,
                                              const int* __restrict__ indexp) {
    if (blockIdx.x < GB) {                             // hop-0 init
        int t = blockIdx.x * 256 + threadIdx.x;
        int d = t & 63;
        int b = t >> 6;
        int row, a;
        batch_row_a(b, indexp[0], users, pos, neg, ua, pa, na, row, a);
        const float* sp = (row < N_USER_C) ? (ue + (int64_t)row * EMB_C)
                                           : (ie + (int64_t)(row - N_USER_C) * EMB_C);
        out[t] = sp[d] / (float)(a + 1);
    } else {                                           // f32 tables -> fp16 ego0
        const int totalU = N_USER_C * EMB_C / 4;
        const int total  = N_NODES_C * EMB_C / 4;
        const int stride = THB * 256;
        const float4* uev = (const float4*)ue;
        const float4* iev = (const float4*)ie;
        for (int i = (blockIdx.x - GB) * 256 + threadIdx.x; i < total; i += stride) {
            float4 v = (i < totalU) ? uev[i] : iev[i - totalU];
            h16x4 h;
            h[0] = (h16)v.x; h[1] = (h16)v.y; h[2] = (h16)v.z; h[3] = (h16)v.w;
            dst[i] = h;
        }
    }
}

// ---------------- fused: hop-1 LDS-SpMM + flags3 seeding ----------------
__global__ __launch_bounds__(256) void k_spmm1x(const int* __restrict__ base2,
                                                const int2* __restrict__ ev,
                                                const h16x4* __restrict__ ego,
                                                h16x4* __restrict__ nxt,
                                                const int* __restrict__ rs,
                                                const int2* __restrict__ ep,
                                                int* __restrict__ flag3,
                                                const int* __restrict__ users,
                                                const int* __restrict__ pos,
                                                const int* __restrict__ neg,
                                                const int* __restrict__ ua,
                                                const int* __restrict__ pa,
                                                const int* __restrict__ na,
                                                const int* __restrict__ indexp) {
    extern __shared__ float accS[];                    // 64 KB dynamic
    if (blockIdx.x < NB) {
        spmm_lds_body(blockIdx.x, threadIdx.x, accS, base2, ev, ego, nxt);
    } else {
        int wid  = ((blockIdx.x - NB) * 256 + threadIdx.x) >> 6;
        int lane = threadIdx.x & 63;
        if (wid >= 3 * BATCH_C) return;
        int row, a;
        batch_row_a(wid, indexp[0], users, pos, neg, ua, pa, na, row, a);
        if (a < 3) return;
        if (lane == 0) flag3[row] = 1;
        if (a == 4) {
            int start = rs[row], end = rs[row + 1];
            for (int e = start + lane; e < end; e += 64)
                flag3[ep[e].x] = 1;                    // benign same-value races
        }
    }
}

// ---------------- fused: hop-2 LDS-SpMM (full) + hop-1 gather ----------------
__global__ __launch_bounds__(256) void k_spmm2x(const int* __restrict__ base2,
                                                const int2* __restrict__ ev,
                                                const h16x4* __restrict__ ego,
                                                h16x4* __restrict__ nxt,
                                                const h16* __restrict__ gsrc,
                                                float* __restrict__ out,
                                                const int* __restrict__ users,
                                                const int* __restrict__ pos,
                                                const int* __restrict__ neg,
                                                const int* __restrict__ ua,
                                                const int* __restrict__ pa,
                                                const int* __restrict__ na,
                                                const int* __restrict__ indexp) {
    extern __shared__ float accS[];
    if (blockIdx.x < NB) {
        spmm_lds_body(blockIdx.x, threadIdx.x, accS, base2, ev, ego, nxt);
    } else {
        int t = (blockIdx.x - NB) * 256 + threadIdx.x;
        gather_body(gsrc, out, t, 1, indexp[0], users, pos, neg, ua, pa, na);
    }
}

// ---------------- fused: hop-3 CSR SpMM (flags3) + hop-2 gather ----------------
__global__ __launch_bounds__(256) void k_spmm3g2(const int* __restrict__ rs,
                                                 const int2* __restrict__ ep,
                                                 const h16x4* __restrict__ ego,
                                                 h16x4* __restrict__ nxt,
                                                 const int* __restrict__ flag3,
                                                 const h16* __restrict__ gsrc,
                                                 float* __restrict__ out,
                                                 const int* __restrict__ users,
                                                 const int* __restrict__ pos,
                                                 const int* __restrict__ neg,
                                                 const int* __restrict__ ua,
                                                 const int* __restrict__ pa,
                                                 const int* __restrict__ na,
                                                 const int* __restrict__ indexp) {
    if (blockIdx.x < SPMM_B) {
        int wid  = (blockIdx.x * 256 + threadIdx.x) >> 6;
        int lane = threadIdx.x & 63;
        spmm_row_body(wid, lane, rs, ep, ego, nxt, flag3);
    } else {
        int t = (blockIdx.x - SPMM_B) * 256 + threadIdx.x;
        gather_body(gsrc, out, t, 2, indexp[0], users, pos, neg, ua, pa, na);
    }
}

// ---------------- fused epilogue: hop-3 gather + hop-4 dot, pre-scaled ----------------
__global__ __launch_bounds__(256) void k_g3g4(const int* __restrict__ rs,
                                              const int2* __restrict__ ep,
                                              const h16x4* __restrict__ ego,   // hop-3 values
                                              float* __restrict__ out,
                                              const int* __restrict__ users,
                                              const int* __restrict__ pos,
                                              const int* __restrict__ neg,
                                              const int* __restrict__ ua,
                                              const int* __restrict__ pa,
                                              const int* __restrict__ na,
                                              const int* __restrict__ indexp) {
    int gid  = blockIdx.x * 256 + threadIdx.x;
    int wid  = gid >> 6;
    int lane = gid & 63;
    if (wid >= 3 * BATCH_C) return;
    int row, a;
    batch_row_a(wid, indexp[0], users, pos, neg, ua, pa, na, row, a);
    if (a < 3) return;
    float4 acc = make_float4(0.f, 0.f, 0.f, 0.f);
    if (a == 4) {
        int start = rs[row], end = rs[row + 1];
        int eo = lane >> 4;
        int l  = lane & 15;
        for (int it = start + eo; it < end; it += 4) {
            int2 p = ep[it];
            float v = __int_as_float(p.y);
            h16x4 g = ego[(int64_t)p.x * 16 + l];
            acc.x += v * (float)g[0]; acc.y += v * (float)g[1];
            acc.z += v * (float)g[2]; acc.w += v * (float)g[3];
        }
        acc.x += __shfl_xor(acc.x, 16); acc.y += __shfl_xor(acc.y, 16);
        acc.z += __shfl_xor(acc.z, 16); acc.w += __shfl_xor(acc.w, 16);
        acc.x += __shfl_xor(acc.x, 32); acc.y += __shfl_xor(acc.y, 32);
        acc.z += __shfl_xor(acc.z, 32); acc.w += __shfl_xor(acc.w, 32);
    }
    if (lane < 16) {                                   // out += (E3 + E4)/(a+1)
        h16x4 g = ego[(int64_t)row * 16 + lane];
        float inv = 1.0f / (float)(a + 1);
        float4* o = (float4*)out + (int64_t)wid * 16 + lane;
        float4 cv = *o;
        cv.x += ((float)g[0] + acc.x) * inv;
        cv.y += ((float)g[1] + acc.y) * inv;
        cv.z += ((float)g[2] + acc.z) * inv;
        cv.w += ((float)g[3] + acc.w) * inv;
        *o = cv;
    }
}

extern "C" void kernel_launch(void* const* d_in, const int* in_sizes, int n_in,
                              void* d_out, int out_size, void* d_ws, size_t ws_size,
                              hipStream_t stream) {
    const float* user_emb = (const float*)d_in[0];
    const float* item_emb = (const float*)d_in[1];
    const float* adj_vals = (const float*)d_in[2];
    const float* drop_u   = (const float*)d_in[3];
    const int*   adj_rows = (const int*)d_in[4];
    const int*   adj_cols = (const int*)d_in[5];
    const int*   users    = (const int*)d_in[6];
    const int*   pos_it   = (const int*)d_in[7];
    const int*   neg_it   = (const int*)d_in[8];
    const int*   u_a      = (const int*)d_in[9];
    const int*   p_a      = (const int*)d_in[10];
    const int*   n_a      = (const int*)d_in[11];
    const int*   indexp   = (const int*)d_in[12];
    float* out = (float*)d_out;

    // workspace layout (~82 MB)
    const size_t egoElems = (size_t)N_NODES_C * EMB_C;       // 9.6M
    h16*   egoH0     = (h16*)d_ws;                           // 19.2 MB
    h16*   bufA      = egoH0 + egoElems;                     // 19.2 MB
    h16*   bufB      = bufA + egoElems;                      // 19.2 MB
    int2*  ep        = (int2*)(bufB + egoElems);             // 9.6 MB (CSR)
    int2*  ev        = ep + NNZ_C;                           // 9.6 MB (slice-grouped)
    int*   row_start = (int*)(ev + NNZ_C);                   // 600 KB (+sentinel)
    int*   cnt2      = row_start + N_NODES_C + 1;            // 1.73 MB
    int*   base2     = cnt2 + N2X + 1;                       // 1.73 MB (+sentinel)
    int*   bsum      = base2 + N2X + 1;                      // ~0.5 KB
    int*   bpre      = bsum + SBLK + 1;                      // ~0.5 KB
    int*   flags3    = bpre + SBLK + 1;                      // 600 KB

    // ---- build: (bucket,slice,block) counting sort ----
    k_bin_count<<<NBLK, 1024, 0, stream>>>(drop_u, adj_rows, adj_cols, cnt2, flags3);
    k_scan_a<<<SBLK, 256, 0, stream>>>(cnt2, bsum);
    k_scan_b<<<1, 128, 0, stream>>>(bsum, bpre, base2, row_start);
    k_scan_c<<<SBLK, 256, 0, stream>>>(cnt2, bpre, base2);
    k_bin_write<<<NBLK, 1024, 0, stream>>>(adj_vals, drop_u, adj_rows, adj_cols,
                                           base2, ev);
    k_bucket_sort<<<NB, 256, 0, stream>>>(ev, base2, ep, row_start);

    // ---- fp16 ego0 + pre-scaled hop-0 init ----
    k_prep<<<GB + THB, 256, 0, stream>>>(user_emb, item_emb, (h16x4*)egoH0, out,
                                         users, pos_it, neg_it, u_a, p_a, n_a, indexp);

    // ---- hop-1 slice-blocked LDS SpMM + flags3 seed ----
    k_spmm1x<<<NB + FB, 256, 65536, stream>>>(base2, ev, (const h16x4*)egoH0,
                                              (h16x4*)bufA, row_start, ep, flags3,
                                              users, pos_it, neg_it, u_a, p_a, n_a, indexp);
    // ---- hop-2 slice-blocked LDS SpMM (full) + hop-1 gather ----
    k_spmm2x<<<NB + GB, 256, 65536, stream>>>(base2, ev, (const h16x4*)bufA,
                                              (h16x4*)bufB, bufA, out,
                                              users, pos_it, neg_it, u_a, p_a, n_a, indexp);
    // ---- hop-3 CSR row-wave (flags3) + hop-2 gather ----
    k_spmm3g2<<<SPMM_B + GB, 256, 0, stream>>>(row_start, ep, (const h16x4*)bufB,
                                               (h16x4*)bufA, flags3, bufB, out,
                                               users, pos_it, neg_it, u_a, p_a, n_a, indexp);
    // ---- hop-3 gather + fused hop-4 dot ----
    k_g3g4<<<GB, 256, 0, stream>>>(row_start, ep, (const h16x4*)bufA, out,
                                   users, pos_it, neg_it, u_a, p_a, n_a, indexp);
}

// Round 12
// 205.499 us; speedup vs baseline: 5.0490x; 5.0490x over previous
//
#include <hip/hip_runtime.h>
#include <stdint.h>

#define N_USER_C  50000
#define N_ITEM_C  100000
#define N_NODES_C 150000
#define EMB_C     64
#define NNZ_C     1200000
#define BATCH_C   4096

#define BKT_SHIFT 9                                   // 512 rows per bucket
#define BKT_ROWS  (1 << BKT_SHIFT)
#define NB        ((N_NODES_C + BKT_ROWS - 1) / BKT_ROWS)   // 293
#define CH        8192                                // edges per binning block
#define NBLK      ((NNZ_C + CH - 1) / CH)             // 147
#define N2        (NB * NBLK)                         // 43071
#define COL_MASK  0x3FFFF                             // 18 bits (N_NODES < 2^18)

#define SPMM_B    37500                               // 150000 waves / 4 per block
#define GB        3072                                // 786432 threads / 256
#define THB       2048                                // tohalf stride blocks
#define FB        3072                                // flag-seed blocks (12288 waves)

typedef _Float16 h16;
typedef _Float16 h16x4 __attribute__((ext_vector_type(4)));

// ---------------- pass A: per-(block,bucket) histogram + flag zeroing ----------------
__global__ __launch_bounds__(1024) void k_bin_count(const float* __restrict__ du,
                                                    const int* __restrict__ rows,
                                                    int* __restrict__ cnt2,
                                                    int* __restrict__ flagz) {
    __shared__ int bk[NB];
    int t = threadIdx.x, blk = blockIdx.x;
    for (int i = blk * 1024 + t; i < 2 * N_NODES_C; i += NBLK * 1024) flagz[i] = 0;
    for (int i = t; i < NB; i += 1024) bk[i] = 0;
    __syncthreads();
    int base = blk * CH;
    for (int i = 0; i < CH; i += 1024) {
        int e = base + i + t;
        if (e < NNZ_C && floorf(0.9f + du[e]) != 0.0f)
            atomicAdd(&bk[rows[e] >> BKT_SHIFT], 1);
    }
    __syncthreads();
    for (int i = t; i < NB; i += 1024) cnt2[i * NBLK + blk] = bk[i];
}

// ---------------- pass B (fused): per-bucket prefix + scan of 147 block counts ----------------
// block i: pre_i = sum(cnt2[0 .. i*NBLK)); then scan own bucket's NBLK counts.
__global__ __launch_bounds__(256) void k_bscan2(const int* __restrict__ cnt2,
                                                int* __restrict__ base2,
                                                int* __restrict__ row_start) {
    __shared__ int red[256];
    __shared__ int sh[256];
    int t = threadIdx.x, i = blockIdx.x;
    // phase 1: bucket-prefix (redundant per block; L2-resident reads)
    int lim = i * NBLK;
    int s = 0;
    for (int idx = t; idx < lim; idx += 256) s += cnt2[idx];
    red[t] = s;
    __syncthreads();
    for (int off = 128; off > 0; off >>= 1) {
        if (t < off) red[t] += red[t + off];
        __syncthreads();
    }
    int pre = red[0];
    // phase 2: scan my bucket's NBLK counts
    int v0 = (t < NBLK) ? cnt2[lim + t] : 0;
    sh[t] = v0;
    __syncthreads();
    for (int off = 1; off < 256; off <<= 1) {
        int v = (t >= off) ? sh[t - off] : 0;
        __syncthreads();
        sh[t] += v;
        __syncthreads();
    }
    if (t < NBLK) base2[lim + t] = pre + sh[t] - v0;
    if (i == NB - 1 && t == NBLK - 1) {                // sentinels: total kept edges
        int total = pre + sh[t];
        base2[N2] = total;
        row_start[N_NODES_C] = total;
    }
}

// ---------------- pass C: bucket-sorted write of packed (rl|col, val) ----------------
__global__ __launch_bounds__(1024) void k_bin_write(const float* __restrict__ av,
                                                    const float* __restrict__ du,
                                                    const int* __restrict__ rows,
                                                    const int* __restrict__ cols,
                                                    const int* __restrict__ base2,
                                                    int2* __restrict__ ev) {
    __shared__ int cur[NB];
    int t = threadIdx.x, blk = blockIdx.x;
    for (int i = t; i < NB; i += 1024) cur[i] = base2[i * NBLK + blk];
    __syncthreads();
    int base = blk * CH;
    for (int i = 0; i < CH; i += 1024) {
        int e = base + i + t;
        if (e < NNZ_C) {
            float m = floorf(0.9f + du[e]);
            if (m != 0.0f) {
                float v = av[e] * m * (float)(1.0 / 0.9);
                int r = rows[e];
                int pos = atomicAdd(&cur[r >> BKT_SHIFT], 1);
                int2 p;
                p.x = ((r & (BKT_ROWS - 1)) << 18) | cols[e];   // rl:9 | col:18
                p.y = __float_as_int(v);
                ev[pos] = p;
            }
        }
    }
}

// ---------------- pass D: per-bucket exact row sort (LDS hist+scan+scatter) ----------------
__global__ __launch_bounds__(256) void k_bucket_sort(const int2* __restrict__ ev,
                                                     const int* __restrict__ base2,
                                                     int2* __restrict__ ep,
                                                     int* __restrict__ row_start) {
    __shared__ int rowcnt[BKT_ROWS];
    __shared__ int cursor[BKT_ROWS];
    __shared__ int tsum[256];
    int t = threadIdx.x, k = blockIdx.x;
    int rowBase = k << BKT_SHIFT;
    int bstart = base2[k * NBLK];
    int bend   = base2[(k + 1) * NBLK];               // k=NB-1 hits base2[N2]=total
    for (int i = t; i < BKT_ROWS; i += 256) rowcnt[i] = 0;
    __syncthreads();
    for (int e = bstart + t; e < bend; e += 256)
        atomicAdd(&rowcnt[((unsigned)ev[e].x) >> 18], 1);
    __syncthreads();
    int a = rowcnt[2 * t], b = rowcnt[2 * t + 1];
    tsum[t] = a + b;
    __syncthreads();
    for (int off = 1; off < 256; off <<= 1) {
        int v = (t >= off) ? tsum[t - off] : 0;
        __syncthreads();
        tsum[t] += v;
        __syncthreads();
    }
    int excl = tsum[t] - (a + b);
    cursor[2 * t]     = excl;
    cursor[2 * t + 1] = excl + a;
    int gr = rowBase + 2 * t;
    if (gr < N_NODES_C)     row_start[gr]     = bstart + excl;
    if (gr + 1 < N_NODES_C) row_start[gr + 1] = bstart + excl + a;
    __syncthreads();
    for (int e = bstart + t; e < bend; e += 256) {
        int2 p = ev[e];
        int rl = ((unsigned)p.x) >> 18;
        int slot = atomicAdd(&cursor[rl], 1);
        p.x &= COL_MASK;                               // strip rl -> clean col
        ep[bstart + slot] = p;
    }
}

// ---------------- shared device helpers ----------------
__device__ __forceinline__ void batch_row_a(int wid, int idx0,
                                            const int* __restrict__ users,
                                            const int* __restrict__ pos,
                                            const int* __restrict__ neg,
                                            const int* __restrict__ ua,
                                            const int* __restrict__ pa,
                                            const int* __restrict__ na,
                                            int& row, int& a) {
    int s = wid >> 12;
    int j = wid & (BATCH_C - 1);
    if (s == 0)      { row = users[j] + (idx0 ? N_USER_C : 0); a = ua[j]; }
    else if (s == 1) { row = pos[j]   + (idx0 ? 0 : N_USER_C); a = pa[j]; }
    else             { row = neg[j]   + (idx0 ? 0 : N_USER_C); a = na[j]; }
}

__device__ __forceinline__ void spmm_row_body(int wid, int lane,
                                              const int* __restrict__ rs,
                                              const int2* __restrict__ ep,
                                              const h16x4* __restrict__ ego,
                                              h16x4* __restrict__ nxt,
                                              const int* __restrict__ flag) {
    if (wid >= N_NODES_C) return;
    if (flag && flag[wid] == 0) return;                // wave-uniform early exit
    int start = rs[wid];
    int end   = rs[wid + 1];
    int eo = lane >> 4;          // edge slot 0..3
    int l  = lane & 15;          // h16x4 index within the 128B row
    float4 acc = make_float4(0.f, 0.f, 0.f, 0.f);
    #pragma unroll 2
    for (int it = start + eo; it < end; it += 4) {
        int2 p = ep[it];
        float v = __int_as_float(p.y);
        h16x4 g = ego[(int64_t)p.x * 16 + l];          // 128B coalesced row gather
        acc.x += v * (float)g[0]; acc.y += v * (float)g[1];
        acc.z += v * (float)g[2]; acc.w += v * (float)g[3];
    }
    acc.x += __shfl_xor(acc.x, 16); acc.y += __shfl_xor(acc.y, 16);
    acc.z += __shfl_xor(acc.z, 16); acc.w += __shfl_xor(acc.w, 16);
    acc.x += __shfl_xor(acc.x, 32); acc.y += __shfl_xor(acc.y, 32);
    acc.z += __shfl_xor(acc.z, 32); acc.w += __shfl_xor(acc.w, 32);
    if (lane < 16) {
        h16x4 h;
        h[0] = (h16)acc.x; h[1] = (h16)acc.y; h[2] = (h16)acc.z; h[3] = (h16)acc.w;
        nxt[(int64_t)wid * 16 + l] = h;
    }
}

// gather-accumulate hop h, pre-scaled by 1/(a+1)
__device__ __forceinline__ void gather_body(const h16* __restrict__ src,
                                            float* __restrict__ out, int t, int hop,
                                            int idx0,
                                            const int* __restrict__ users,
                                            const int* __restrict__ pos,
                                            const int* __restrict__ neg,
                                            const int* __restrict__ ua,
                                            const int* __restrict__ pa,
                                            const int* __restrict__ na) {
    int d = t & 63;
    int b = t >> 6;
    int row, a;
    batch_row_a(b, idx0, users, pos, neg, ua, pa, na, row, a);
    if (hop <= a)
        out[t] += (float)src[(int64_t)row * EMB_C + d] / (float)(a + 1);
}

// ---------------- fused: fp16 conversion + pre-scaled hop-0 init + flag seeding ----------------
__global__ __launch_bounds__(256) void k_prep(const float* __restrict__ ue,
                                              const float* __restrict__ ie,
                                              h16x4* __restrict__ dst,
                                              float* __restrict__ out,
                                              const int* __restrict__ rs,
                                              const int2* __restrict__ ep,
                                              int* __restrict__ flag3,
                                              int* __restrict__ flag2,
                                              const int* __restrict__ users,
                                              const int* __restrict__ pos,
                                              const int* __restrict__ neg,
                                              const int* __restrict__ ua,
                                              const int* __restrict__ pa,
                                              const int* __restrict__ na,
                                              const int* __restrict__ indexp) {
    if (blockIdx.x < GB) {                             // hop-0 init (all of out)
        int t = blockIdx.x * 256 + threadIdx.x;
        int d = t & 63;
        int b = t >> 6;
        int row, a;
        batch_row_a(b, indexp[0], users, pos, neg, ua, pa, na, row, a);
        const float* sp = (row < N_USER_C) ? (ue + (int64_t)row * EMB_C)
                                           : (ie + (int64_t)(row - N_USER_C) * EMB_C);
        out[t] = sp[d] / (float)(a + 1);
    } else if (blockIdx.x < GB + THB) {                // f32 tables -> fp16 ego0
        const int totalU = N_USER_C * EMB_C / 4;
        const int total  = N_NODES_C * EMB_C / 4;
        const int stride = THB * 256;
        const float4* uev = (const float4*)ue;
        const float4* iev = (const float4*)ie;
        for (int i = (blockIdx.x - GB) * 256 + threadIdx.x; i < total; i += stride) {
            float4 v = (i < totalU) ? uev[i] : iev[i - totalU];
            h16x4 h;
            h[0] = (h16)v.x; h[1] = (h16)v.y; h[2] = (h16)v.z; h[3] = (h16)v.w;
            dst[i] = h;
        }
    } else {                                           // need-flag seeding
        int wid  = ((blockIdx.x - GB - THB) * 256 + threadIdx.x) >> 6;
        int lane = threadIdx.x & 63;
        if (wid >= 3 * BATCH_C) return;
        int row, a;
        batch_row_a(wid, indexp[0], users, pos, neg, ua, pa, na, row, a);
        if (a < 2) return;
        if (lane == 0) {
            flag2[row] = 1;                            // hop-2 gathered for a>=2
            if (a >= 3) flag3[row] = 1;                // hop-3 gathered for a>=3
        }
        if (a == 4) {                                  // cols read by hop-4 dot
            int start = rs[row], end = rs[row + 1];
            for (int e = start + lane; e < end; e += 64)
                flag3[ep[e].x] = 1;                    // benign same-value races
        }
    }
}

// ---------------- hop-1 full SpMM (clean grid) ----------------
__global__ __launch_bounds__(256) void k_spmm1(const int* __restrict__ rs,
                                               const int2* __restrict__ ep,
                                               const h16x4* __restrict__ ego,
                                               h16x4* __restrict__ nxt) {
    int wid  = (blockIdx.x * 256 + threadIdx.x) >> 6;
    int lane = threadIdx.x & 63;
    spmm_row_body(wid, lane, rs, ep, ego, nxt, (const int*)nullptr);
}

// ---------------- fused: flags2 |= N(flags3)  +  hop-1 gather ----------------
__global__ __launch_bounds__(256) void k_fg1(const int* __restrict__ rs,
                                             const int2* __restrict__ ep,
                                             const int* __restrict__ flag3,
                                             int* __restrict__ flag2,
                                             const h16* __restrict__ src,
                                             float* __restrict__ out,
                                             const int* __restrict__ users,
                                             const int* __restrict__ pos,
                                             const int* __restrict__ neg,
                                             const int* __restrict__ ua,
                                             const int* __restrict__ pa,
                                             const int* __restrict__ na,
                                             const int* __restrict__ indexp) {
    if (blockIdx.x < SPMM_B) {                         // flags2 expansion
        int wid  = (blockIdx.x * 256 + threadIdx.x) >> 6;
        int lane = threadIdx.x & 63;
        if (wid >= N_NODES_C || flag3[wid] == 0) return;
        int start = rs[wid], end = rs[wid + 1];
        for (int e = start + lane; e < end; e += 64)
            flag2[ep[e].x] = 1;                        // benign same-value races
    } else {                                           // hop-1 gather
        int t = (blockIdx.x - SPMM_B) * 256 + threadIdx.x;
        gather_body(src, out, t, 1, indexp[0], users, pos, neg, ua, pa, na);
    }
}

// ---------------- hop-2 SpMM (flags2-pruned) ----------------
__global__ __launch_bounds__(256) void k_spmm2(const int* __restrict__ rs,
                                               const int2* __restrict__ ep,
                                               const h16x4* __restrict__ ego,
                                               h16x4* __restrict__ nxt,
                                               const int* __restrict__ flag) {
    int wid  = (blockIdx.x * 256 + threadIdx.x) >> 6;
    int lane = threadIdx.x & 63;
    spmm_row_body(wid, lane, rs, ep, ego, nxt, flag);
}

// ---------------- fused: hop-3 SpMM (flags3) + hop-2 gather ----------------
__global__ __launch_bounds__(256) void k_spmm3g2(const int* __restrict__ rs,
                                                 const int2* __restrict__ ep,
                                                 const h16x4* __restrict__ ego,
                                                 h16x4* __restrict__ nxt,
                                                 const int* __restrict__ flag3,
                                                 const h16* __restrict__ gsrc,
                                                 float* __restrict__ out,
                                                 const int* __restrict__ users,
                                                 const int* __restrict__ pos,
                                                 const int* __restrict__ neg,
                                                 const int* __restrict__ ua,
                                                 const int* __restrict__ pa,
                                                 const int* __restrict__ na,
                                                 const int* __restrict__ indexp) {
    if (blockIdx.x < SPMM_B) {
        int wid  = (blockIdx.x * 256 + threadIdx.x) >> 6;
        int lane = threadIdx.x & 63;
        spmm_row_body(wid, lane, rs, ep, ego, nxt, flag3);
    } else {
        int t = (blockIdx.x - SPMM_B) * 256 + threadIdx.x;
        gather_body(gsrc, out, t, 2, indexp[0], users, pos, neg, ua, pa, na);
    }
}

// ---------------- fused epilogue: hop-3 gather + hop-4 dot, pre-scaled ----------------
__global__ __launch_bounds__(256) void k_g3g4(const int* __restrict__ rs,
                                              const int2* __restrict__ ep,
                                              const h16x4* __restrict__ ego,   // hop-3 values
                                              float* __restrict__ out,
                                              const int* __restrict__ users,
                                              const int* __restrict__ pos,
                                              const int* __restrict__ neg,
                                              const int* __restrict__ ua,
                                              const int* __restrict__ pa,
                                              const int* __restrict__ na,
                                              const int* __restrict__ indexp) {
    int gid  = blockIdx.x * 256 + threadIdx.x;
    int wid  = gid >> 6;                               // batch slot
    int lane = gid & 63;
    if (wid >= 3 * BATCH_C) return;
    int row, a;
    batch_row_a(wid, indexp[0], users, pos, neg, ua, pa, na, row, a);
    if (a < 3) return;                                 // wave-uniform
    float4 acc = make_float4(0.f, 0.f, 0.f, 0.f);
    if (a == 4) {                                      // E4 = (A*E3)[row]
        int start = rs[row], end = rs[row + 1];
        int eo = lane >> 4;
        int l  = lane & 15;
        for (int it = start + eo; it < end; it += 4) {
            int2 p = ep[it];
            float v = __int_as_float(p.y);
            h16x4 g = ego[(int64_t)p.x * 16 + l];
            acc.x += v * (float)g[0]; acc.y += v * (float)g[1];
            acc.z += v * (float)g[2]; acc.w += v * (float)g[3];
        }
        acc.x += __shfl_xor(acc.x, 16); acc.y += __shfl_xor(acc.y, 16);
        acc.z += __shfl_xor(acc.z, 16); acc.w += __shfl_xor(acc.w, 16);
        acc.x += __shfl_xor(acc.x, 32); acc.y += __shfl_xor(acc.y, 32);
        acc.z += __shfl_xor(acc.z, 32); acc.w += __shfl_xor(acc.w, 32);
    }
    if (lane < 16) {                                   // out += (E3 + E4) / (a+1)
        h16x4 g = ego[(int64_t)row * 16 + lane];
        float inv = 1.0f / (float)(a + 1);
        float4* o = (float4*)out + (int64_t)wid * 16 + lane;
        float4 cv = *o;
        cv.x += ((float)g[0] + acc.x) * inv;
        cv.y += ((float)g[1] + acc.y) * inv;
        cv.z += ((float)g[2] + acc.z) * inv;
        cv.w += ((float)g[3] + acc.w) * inv;
        *o = cv;
    }
}

extern "C" void kernel_launch(void* const* d_in, const int* in_sizes, int n_in,
                              void* d_out, int out_size, void* d_ws, size_t ws_size,
                              hipStream_t stream) {
    const float* user_emb = (const float*)d_in[0];
    const float* item_emb = (const float*)d_in[1];
    const float* adj_vals = (const float*)d_in[2];
    const float* drop_u   = (const float*)d_in[3];
    const int*   adj_rows = (const int*)d_in[4];
    const int*   adj_cols = (const int*)d_in[5];
    const int*   users    = (const int*)d_in[6];
    const int*   pos_it   = (const int*)d_in[7];
    const int*   neg_it   = (const int*)d_in[8];
    const int*   u_a      = (const int*)d_in[9];
    const int*   p_a      = (const int*)d_in[10];
    const int*   n_a      = (const int*)d_in[11];
    const int*   indexp   = (const int*)d_in[12];
    float* out = (float*)d_out;

    // workspace layout (~79 MB)
    const size_t egoElems = (size_t)N_NODES_C * EMB_C;       // 9.6M
    h16*   egoH0     = (h16*)d_ws;                           // 19.2 MB
    h16*   bufA      = egoH0 + egoElems;                     // 19.2 MB
    h16*   bufB      = bufA + egoElems;                      // 19.2 MB
    int2*  ep        = (int2*)(bufB + egoElems);             // 9.6 MB (final CSR)
    int2*  ev        = ep + NNZ_C;                           // 9.6 MB (build tmp)
    int*   row_start = (int*)(ev + NNZ_C);                   // 600 KB (+sentinel)
    int*   cnt2      = row_start + N_NODES_C + 1;            // ~172 KB
    int*   base2     = cnt2 + N2 + 1;                        // ~172 KB (+sentinel)
    int*   flags3    = base2 + N2 + 1;                       // 600 KB
    int*   flags2    = flags3 + N_NODES_C;                   // 600 KB (contiguous)

    // ---- CSR build (4 dispatches); flags zeroed inside bin_count ----
    k_bin_count<<<NBLK, 1024, 0, stream>>>(drop_u, adj_rows, cnt2, flags3);
    k_bscan2<<<NB, 256, 0, stream>>>(cnt2, base2, row_start);
    k_bin_write<<<NBLK, 1024, 0, stream>>>(adj_vals, drop_u, adj_rows, adj_cols,
                                           base2, ev);
    k_bucket_sort<<<NB, 256, 0, stream>>>(ev, base2, ep, row_start);

    // ---- fp16 ego0 + pre-scaled hop-0 init + flag seeding (1 dispatch) ----
    k_prep<<<GB + THB + FB, 256, 0, stream>>>(user_emb, item_emb, (h16x4*)egoH0, out,
                                              row_start, ep, flags3, flags2,
                                              users, pos_it, neg_it, u_a, p_a, n_a, indexp);

    // ---- hop-1 full SpMM (clean grid) ----
    k_spmm1<<<SPMM_B, 256, 0, stream>>>(row_start, ep, (const h16x4*)egoH0,
                                        (h16x4*)bufA);
    // ---- flags2 expansion + hop-1 gather ----
    k_fg1<<<SPMM_B + GB, 256, 0, stream>>>(row_start, ep, flags3, flags2,
                                           bufA, out,
                                           users, pos_it, neg_it, u_a, p_a, n_a, indexp);
    // ---- hop-2 SpMM, flags2-pruned ----
    k_spmm2<<<SPMM_B, 256, 0, stream>>>(row_start, ep, (const h16x4*)bufA,
                                        (h16x4*)bufB, flags2);
    // ---- hop-3 SpMM (flags3) + hop-2 gather ----
    k_spmm3g2<<<SPMM_B + GB, 256, 0, stream>>>(row_start, ep, (const h16x4*)bufB,
                                               (h16x4*)bufA, flags3, bufB, out,
                                               users, pos_it, neg_it, u_a, p_a, n_a, indexp);
    // ---- hop-3 gather + fused hop-4 dot ----
    k_g3g4<<<GB, 256, 0, stream>>>(row_start, ep, (const h16x4*)bufA, out,
                                   users, pos_it, neg_it, u_a, p_a, n_a, indexp);
}

// Round 13
// 192.064 us; speedup vs baseline: 5.4022x; 1.0699x over previous
//
#include <hip/hip_runtime.h>
#include <stdint.h>

#define N_USER_C  50000
#define N_ITEM_C  100000
#define N_NODES_C 150000
#define EMB_C     64
#define NNZ_C     1200000
#define BATCH_C   4096

#define BKT_SHIFT 9                                   // 512 rows per bucket
#define BKT_ROWS  (1 << BKT_SHIFT)
#define NB        ((N_NODES_C + BKT_ROWS - 1) / BKT_ROWS)   // 293
#define CH        8192                                // edges per binning block
#define NBLK      ((NNZ_C + CH - 1) / CH)             // 147
#define N2        (NB * NBLK)                         // 43071
#define COL_MASK  0x3FFFF                             // 18 bits (N_NODES < 2^18)

#define SPMM_B    37500                               // 150000 waves / 4 per block
#define GB        3072                                // 786432 threads / 256
#define THB       2048                                // tohalf stride blocks
#define FB        3072                                // flag-seed blocks (12288 waves)

typedef _Float16 h16;
typedef _Float16 h16x4 __attribute__((ext_vector_type(4)));

// ---------------- pass A: per-(block,bucket) histogram + flag zeroing ----------------
__global__ __launch_bounds__(1024) void k_bin_count(const float* __restrict__ du,
                                                    const int* __restrict__ rows,
                                                    int* __restrict__ cnt2,
                                                    int* __restrict__ flagz) {
    __shared__ int bk[NB];
    int t = threadIdx.x, blk = blockIdx.x;
    for (int i = blk * 1024 + t; i < 2 * N_NODES_C; i += NBLK * 1024) flagz[i] = 0;
    for (int i = t; i < NB; i += 1024) bk[i] = 0;
    __syncthreads();
    int base = blk * CH;
    for (int i = 0; i < CH; i += 1024) {
        int e = base + i + t;
        if (e < NNZ_C && floorf(0.9f + du[e]) != 0.0f)
            atomicAdd(&bk[rows[e] >> BKT_SHIFT], 1);
    }
    __syncthreads();
    for (int i = t; i < NB; i += 1024) cnt2[i * NBLK + blk] = bk[i];
}

// ---------------- pass B1: bucket totals + scan of 293 (round-10 proven) ----------------
__global__ __launch_bounds__(512) void k_bbase(const int* __restrict__ cnt2,
                                               int* __restrict__ bbase,
                                               int* __restrict__ base2,
                                               int* __restrict__ row_start) {
    __shared__ int sh[512];
    int t = threadIdx.x;
    int s = 0;
    if (t < NB) {
        const int* p = cnt2 + t * NBLK;
        for (int i = 0; i < NBLK; ++i) s += p[i];
    }
    sh[t] = s;
    __syncthreads();
    for (int off = 1; off < 512; off <<= 1) {
        int v = (t >= off) ? sh[t - off] : 0;
        __syncthreads();
        sh[t] += v;
        __syncthreads();
    }
    if (t < NB) bbase[t] = sh[t] - s;                  // exclusive bucket prefix
    if (t == 511) {
        base2[N2] = sh[511];                           // total kept edges
        row_start[N_NODES_C] = sh[511];                // CSR sentinel
    }
}

// ---------------- pass B2: per-bucket scan of 147 block counts ----------------
__global__ __launch_bounds__(256) void k_bscan(const int* __restrict__ cnt2,
                                               const int* __restrict__ bbase,
                                               int* __restrict__ base2) {
    __shared__ int sh[256];
    int t = threadIdx.x, i = blockIdx.x;
    int v0 = (t < NBLK) ? cnt2[i * NBLK + t] : 0;
    sh[t] = v0;
    __syncthreads();
    for (int off = 1; off < 256; off <<= 1) {
        int v = (t >= off) ? sh[t - off] : 0;
        __syncthreads();
        sh[t] += v;
        __syncthreads();
    }
    if (t < NBLK) base2[i * NBLK + t] = bbase[i] + sh[t] - v0;
}

// ---------------- pass C: bucket-sorted write of packed (rl|col, val) ----------------
__global__ __launch_bounds__(1024) void k_bin_write(const float* __restrict__ av,
                                                    const float* __restrict__ du,
                                                    const int* __restrict__ rows,
                                                    const int* __restrict__ cols,
                                                    const int* __restrict__ base2,
                                                    int2* __restrict__ ev) {
    __shared__ int cur[NB];
    int t = threadIdx.x, blk = blockIdx.x;
    for (int i = t; i < NB; i += 1024) cur[i] = base2[i * NBLK + blk];
    __syncthreads();
    int base = blk * CH;
    for (int i = 0; i < CH; i += 1024) {
        int e = base + i + t;
        if (e < NNZ_C) {
            float m = floorf(0.9f + du[e]);
            if (m != 0.0f) {
                float v = av[e] * m * (float)(1.0 / 0.9);
                int r = rows[e];
                int pos = atomicAdd(&cur[r >> BKT_SHIFT], 1);
                int2 p;
                p.x = ((r & (BKT_ROWS - 1)) << 18) | cols[e];   // rl:9 | col:18
                p.y = __float_as_int(v);
                ev[pos] = p;
            }
        }
    }
}

// ---------------- pass D: per-bucket exact row sort (LDS hist+scan+scatter) ----------------
__global__ __launch_bounds__(256) void k_bucket_sort(const int2* __restrict__ ev,
                                                     const int* __restrict__ base2,
                                                     int2* __restrict__ ep,
                                                     int* __restrict__ row_start) {
    __shared__ int rowcnt[BKT_ROWS];
    __shared__ int cursor[BKT_ROWS];
    __shared__ int tsum[256];
    int t = threadIdx.x, k = blockIdx.x;
    int rowBase = k << BKT_SHIFT;
    int bstart = base2[k * NBLK];
    int bend   = base2[(k + 1) * NBLK];               // k=NB-1 hits base2[N2]=total
    for (int i = t; i < BKT_ROWS; i += 256) rowcnt[i] = 0;
    __syncthreads();
    for (int e = bstart + t; e < bend; e += 256)
        atomicAdd(&rowcnt[((unsigned)ev[e].x) >> 18], 1);
    __syncthreads();
    int a = rowcnt[2 * t], b = rowcnt[2 * t + 1];
    tsum[t] = a + b;
    __syncthreads();
    for (int off = 1; off < 256; off <<= 1) {
        int v = (t >= off) ? tsum[t - off] : 0;
        __syncthreads();
        tsum[t] += v;
        __syncthreads();
    }
    int excl = tsum[t] - (a + b);
    cursor[2 * t]     = excl;
    cursor[2 * t + 1] = excl + a;
    int gr = rowBase + 2 * t;
    if (gr < N_NODES_C)     row_start[gr]     = bstart + excl;
    if (gr + 1 < N_NODES_C) row_start[gr + 1] = bstart + excl + a;
    __syncthreads();
    for (int e = bstart + t; e < bend; e += 256) {
        int2 p = ev[e];
        int rl = ((unsigned)p.x) >> 18;
        int slot = atomicAdd(&cursor[rl], 1);
        p.x &= COL_MASK;                               // strip rl -> clean col
        ep[bstart + slot] = p;
    }
}

// ---------------- shared device helpers ----------------
__device__ __forceinline__ void batch_row_a(int wid, int idx0,
                                            const int* __restrict__ users,
                                            const int* __restrict__ pos,
                                            const int* __restrict__ neg,
                                            const int* __restrict__ ua,
                                            const int* __restrict__ pa,
                                            const int* __restrict__ na,
                                            int& row, int& a) {
    int s = wid >> 12;
    int j = wid & (BATCH_C - 1);
    if (s == 0)      { row = users[j] + (idx0 ? N_USER_C : 0); a = ua[j]; }
    else if (s == 1) { row = pos[j]   + (idx0 ? 0 : N_USER_C); a = pa[j]; }
    else             { row = neg[j]   + (idx0 ? 0 : N_USER_C); a = na[j]; }
}

__device__ __forceinline__ void spmm_row_body(int wid, int lane,
                                              const int* __restrict__ rs,
                                              const int2* __restrict__ ep,
                                              const h16x4* __restrict__ ego,
                                              h16x4* __restrict__ nxt,
                                              const int* __restrict__ flag) {
    if (wid >= N_NODES_C) return;
    if (flag && flag[wid] == 0) return;                // wave-uniform early exit
    int start = rs[wid];
    int end   = rs[wid + 1];
    int eo = lane >> 4;          // edge slot 0..3
    int l  = lane & 15;          // h16x4 index within the 128B row
    float4 acc = make_float4(0.f, 0.f, 0.f, 0.f);
    #pragma unroll 2
    for (int it = start + eo; it < end; it += 4) {
        int2 p = ep[it];
        float v = __int_as_float(p.y);
        h16x4 g = ego[(int64_t)p.x * 16 + l];          // 128B coalesced row gather
        acc.x += v * (float)g[0]; acc.y += v * (float)g[1];
        acc.z += v * (float)g[2]; acc.w += v * (float)g[3];
    }
    acc.x += __shfl_xor(acc.x, 16); acc.y += __shfl_xor(acc.y, 16);
    acc.z += __shfl_xor(acc.z, 16); acc.w += __shfl_xor(acc.w, 16);
    acc.x += __shfl_xor(acc.x, 32); acc.y += __shfl_xor(acc.y, 32);
    acc.z += __shfl_xor(acc.z, 32); acc.w += __shfl_xor(acc.w, 32);
    if (lane < 16) {
        h16x4 h;
        h[0] = (h16)acc.x; h[1] = (h16)acc.y; h[2] = (h16)acc.z; h[3] = (h16)acc.w;
        nxt[(int64_t)wid * 16 + l] = h;
    }
}

// gather-accumulate hop h, pre-scaled by 1/(a+1)
__device__ __forceinline__ void gather_body(const h16* __restrict__ src,
                                            float* __restrict__ out, int t, int hop,
                                            int idx0,
                                            const int* __restrict__ users,
                                            const int* __restrict__ pos,
                                            const int* __restrict__ neg,
                                            const int* __restrict__ ua,
                                            const int* __restrict__ pa,
                                            const int* __restrict__ na) {
    int d = t & 63;
    int b = t >> 6;
    int row, a;
    batch_row_a(b, idx0, users, pos, neg, ua, pa, na, row, a);
    if (hop <= a)
        out[t] += (float)src[(int64_t)row * EMB_C + d] / (float)(a + 1);
}

// ---------------- fused: fp16 conversion + pre-scaled hop-0 init + flag seeding ----------------
__global__ __launch_bounds__(256) void k_prep(const float* __restrict__ ue,
                                              const float* __restrict__ ie,
                                              h16x4* __restrict__ dst,
                                              float* __restrict__ out,
                                              const int* __restrict__ rs,
                                              const int2* __restrict__ ep,
                                              int* __restrict__ flag3,
                                              int* __restrict__ flag2,
                                              const int* __restrict__ users,
                                              const int* __restrict__ pos,
                                              const int* __restrict__ neg,
                                              const int* __restrict__ ua,
                                              const int* __restrict__ pa,
                                              const int* __restrict__ na,
                                              const int* __restrict__ indexp) {
    if (blockIdx.x < GB) {                             // hop-0 init (all of out)
        int t = blockIdx.x * 256 + threadIdx.x;
        int d = t & 63;
        int b = t >> 6;
        int row, a;
        batch_row_a(b, indexp[0], users, pos, neg, ua, pa, na, row, a);
        const float* sp = (row < N_USER_C) ? (ue + (int64_t)row * EMB_C)
                                           : (ie + (int64_t)(row - N_USER_C) * EMB_C);
        out[t] = sp[d] / (float)(a + 1);
    } else if (blockIdx.x < GB + THB) {                // f32 tables -> fp16 ego0
        const int totalU = N_USER_C * EMB_C / 4;
        const int total  = N_NODES_C * EMB_C / 4;
        const int stride = THB * 256;
        const float4* uev = (const float4*)ue;
        const float4* iev = (const float4*)ie;
        for (int i = (blockIdx.x - GB) * 256 + threadIdx.x; i < total; i += stride) {
            float4 v = (i < totalU) ? uev[i] : iev[i - totalU];
            h16x4 h;
            h[0] = (h16)v.x; h[1] = (h16)v.y; h[2] = (h16)v.z; h[3] = (h16)v.w;
            dst[i] = h;
        }
    } else {                                           // need-flag seeding
        int wid  = ((blockIdx.x - GB - THB) * 256 + threadIdx.x) >> 6;
        int lane = threadIdx.x & 63;
        if (wid >= 3 * BATCH_C) return;
        int row, a;
        batch_row_a(wid, indexp[0], users, pos, neg, ua, pa, na, row, a);
        if (a < 2) return;
        if (lane == 0) {
            flag2[row] = 1;                            // hop-2 gathered for a>=2
            if (a >= 3) flag3[row] = 1;                // hop-3 gathered for a>=3
        }
        if (a == 4) {                                  // cols read by hop-4 dot
            int start = rs[row], end = rs[row + 1];
            for (int e = start + lane; e < end; e += 64)
                flag3[ep[e].x] = 1;                    // benign same-value races
        }
    }
}

// ---------------- fused: hop-1 full SpMM  ∥  flags2 |= N(flags3) ----------------
__global__ __launch_bounds__(256) void k_spmm1f(const int* __restrict__ rs,
                                                const int2* __restrict__ ep,
                                                const h16x4* __restrict__ ego,
                                                h16x4* __restrict__ nxt,
                                                const int* __restrict__ flag3,
                                                int* __restrict__ flag2) {
    int lane = threadIdx.x & 63;
    if (blockIdx.x < SPMM_B) {                         // full hop-1 SpMM
        int wid = (blockIdx.x * 256 + threadIdx.x) >> 6;
        spmm_row_body(wid, lane, rs, ep, ego, nxt, (const int*)nullptr);
    } else {                                           // flags2 expansion (hidden)
        int wid = ((blockIdx.x - SPMM_B) * 256 + threadIdx.x) >> 6;
        if (wid >= N_NODES_C || flag3[wid] == 0) return;
        int start = rs[wid], end = rs[wid + 1];
        for (int e = start + lane; e < end; e += 64)
            flag2[ep[e].x] = 1;                        // benign same-value races
    }
}

// ---------------- fused: hop-2 SpMM (flags2)  ∥  hop-1 gather ----------------
__global__ __launch_bounds__(256) void k_spmm2g1(const int* __restrict__ rs,
                                                 const int2* __restrict__ ep,
                                                 const h16x4* __restrict__ ego,
                                                 h16x4* __restrict__ nxt,
                                                 const int* __restrict__ flag2,
                                                 const h16* __restrict__ gsrc,
                                                 float* __restrict__ out,
                                                 const int* __restrict__ users,
                                                 const int* __restrict__ pos,
                                                 const int* __restrict__ neg,
                                                 const int* __restrict__ ua,
                                                 const int* __restrict__ pa,
                                                 const int* __restrict__ na,
                                                 const int* __restrict__ indexp) {
    if (blockIdx.x < SPMM_B) {
        int wid  = (blockIdx.x * 256 + threadIdx.x) >> 6;
        int lane = threadIdx.x & 63;
        spmm_row_body(wid, lane, rs, ep, ego, nxt, flag2);
    } else {
        int t = (blockIdx.x - SPMM_B) * 256 + threadIdx.x;
        gather_body(gsrc, out, t, 1, indexp[0], users, pos, neg, ua, pa, na);
    }
}

// ---------------- fused: hop-3 SpMM (flags3)  ∥  hop-2 gather ----------------
__global__ __launch_bounds__(256) void k_spmm3g2(const int* __restrict__ rs,
                                                 const int2* __restrict__ ep,
                                                 const h16x4* __restrict__ ego,
                                                 h16x4* __restrict__ nxt,
                                                 const int* __restrict__ flag3,
                                                 const h16* __restrict__ gsrc,
                                                 float* __restrict__ out,
                                                 const int* __restrict__ users,
                                                 const int* __restrict__ pos,
                                                 const int* __restrict__ neg,
                                                 const int* __restrict__ ua,
                                                 const int* __restrict__ pa,
                                                 const int* __restrict__ na,
                                                 const int* __restrict__ indexp) {
    if (blockIdx.x < SPMM_B) {
        int wid  = (blockIdx.x * 256 + threadIdx.x) >> 6;
        int lane = threadIdx.x & 63;
        spmm_row_body(wid, lane, rs, ep, ego, nxt, flag3);
    } else {
        int t = (blockIdx.x - SPMM_B) * 256 + threadIdx.x;
        gather_body(gsrc, out, t, 2, indexp[0], users, pos, neg, ua, pa, na);
    }
}

// ---------------- fused epilogue: hop-3 gather + hop-4 dot, pre-scaled ----------------
__global__ __launch_bounds__(256) void k_g3g4(const int* __restrict__ rs,
                                              const int2* __restrict__ ep,
                                              const h16x4* __restrict__ ego,   // hop-3 values
                                              float* __restrict__ out,
                                              const int* __restrict__ users,
                                              const int* __restrict__ pos,
                                              const int* __restrict__ neg,
                                              const int* __restrict__ ua,
                                              const int* __restrict__ pa,
                                              const int* __restrict__ na,
                                              const int* __restrict__ indexp) {
    int gid  = blockIdx.x * 256 + threadIdx.x;
    int wid  = gid >> 6;                               // batch slot
    int lane = gid & 63;
    if (wid >= 3 * BATCH_C) return;
    int row, a;
    batch_row_a(wid, indexp[0], users, pos, neg, ua, pa, na, row, a);
    if (a < 3) return;                                 // wave-uniform
    float4 acc = make_float4(0.f, 0.f, 0.f, 0.f);
    if (a == 4) {                                      // E4 = (A*E3)[row]
        int start = rs[row], end = rs[row + 1];
        int eo = lane >> 4;
        int l  = lane & 15;
        for (int it = start + eo; it < end; it += 4) {
            int2 p = ep[it];
            float v = __int_as_float(p.y);
            h16x4 g = ego[(int64_t)p.x * 16 + l];
            acc.x += v * (float)g[0]; acc.y += v * (float)g[1];
            acc.z += v * (float)g[2]; acc.w += v * (float)g[3];
        }
        acc.x += __shfl_xor(acc.x, 16); acc.y += __shfl_xor(acc.y, 16);
        acc.z += __shfl_xor(acc.z, 16); acc.w += __shfl_xor(acc.w, 16);
        acc.x += __shfl_xor(acc.x, 32); acc.y += __shfl_xor(acc.y, 32);
        acc.z += __shfl_xor(acc.z, 32); acc.w += __shfl_xor(acc.w, 32);
    }
    if (lane < 16) {                                   // out += (E3 + E4) / (a+1)
        h16x4 g = ego[(int64_t)row * 16 + lane];
        float inv = 1.0f / (float)(a + 1);
        float4* o = (float4*)out + (int64_t)wid * 16 + lane;
        float4 cv = *o;
        cv.x += ((float)g[0] + acc.x) * inv;
        cv.y += ((float)g[1] + acc.y) * inv;
        cv.z += ((float)g[2] + acc.z) * inv;
        cv.w += ((float)g[3] + acc.w) * inv;
        *o = cv;
    }
}

extern "C" void kernel_launch(void* const* d_in, const int* in_sizes, int n_in,
                              void* d_out, int out_size, void* d_ws, size_t ws_size,
                              hipStream_t stream) {
    const float* user_emb = (const float*)d_in[0];
    const float* item_emb = (const float*)d_in[1];
    const float* adj_vals = (const float*)d_in[2];
    const float* drop_u   = (const float*)d_in[3];
    const int*   adj_rows = (const int*)d_in[4];
    const int*   adj_cols = (const int*)d_in[5];
    const int*   users    = (const int*)d_in[6];
    const int*   pos_it   = (const int*)d_in[7];
    const int*   neg_it   = (const int*)d_in[8];
    const int*   u_a      = (const int*)d_in[9];
    const int*   p_a      = (const int*)d_in[10];
    const int*   n_a      = (const int*)d_in[11];
    const int*   indexp   = (const int*)d_in[12];
    float* out = (float*)d_out;

    // workspace layout (~79 MB)
    const size_t egoElems = (size_t)N_NODES_C * EMB_C;       // 9.6M
    h16*   egoH0     = (h16*)d_ws;                           // 19.2 MB
    h16*   bufA      = egoH0 + egoElems;                     // 19.2 MB
    h16*   bufB      = bufA + egoElems;                      // 19.2 MB
    int2*  ep        = (int2*)(bufB + egoElems);             // 9.6 MB (final CSR)
    int2*  ev        = ep + NNZ_C;                           // 9.6 MB (build tmp)
    int*   row_start = (int*)(ev + NNZ_C);                   // 600 KB (+sentinel)
    int*   cnt2      = row_start + N_NODES_C + 1;            // ~172 KB
    int*   base2     = cnt2 + N2 + 1;                        // ~172 KB (+sentinel)
    int*   bbase     = base2 + N2 + 1;                       // ~1.2 KB
    int*   flags3    = bbase + NB + 1;                       // 600 KB
    int*   flags2    = flags3 + N_NODES_C;                   // 600 KB (contiguous)

    // ---- CSR build (5 dispatches, round-10 proven); flags zeroed inside bin_count ----
    k_bin_count<<<NBLK, 1024, 0, stream>>>(drop_u, adj_rows, cnt2, flags3);
    k_bbase<<<1, 512, 0, stream>>>(cnt2, bbase, base2, row_start);
    k_bscan<<<NB, 256, 0, stream>>>(cnt2, bbase, base2);
    k_bin_write<<<NBLK, 1024, 0, stream>>>(adj_vals, drop_u, adj_rows, adj_cols,
                                           base2, ev);
    k_bucket_sort<<<NB, 256, 0, stream>>>(ev, base2, ep, row_start);

    // ---- fp16 ego0 + pre-scaled hop-0 init + flag seeding (1 dispatch) ----
    k_prep<<<GB + THB + FB, 256, 0, stream>>>(user_emb, item_emb, (h16x4*)egoH0, out,
                                              row_start, ep, flags3, flags2,
                                              users, pos_it, neg_it, u_a, p_a, n_a, indexp);

    // ---- hop-1 full SpMM ∥ flags2 expansion (hidden under SpMM) ----
    k_spmm1f<<<SPMM_B + SPMM_B, 256, 0, stream>>>(row_start, ep, (const h16x4*)egoH0,
                                                  (h16x4*)bufA, flags3, flags2);
    // ---- hop-2 SpMM (flags2) ∥ hop-1 gather ----
    k_spmm2g1<<<SPMM_B + GB, 256, 0, stream>>>(row_start, ep, (const h16x4*)bufA,
                                               (h16x4*)bufB, flags2, bufA, out,
                                               users, pos_it, neg_it, u_a, p_a, n_a, indexp);
    // ---- hop-3 SpMM (flags3) ∥ hop-2 gather ----
    k_spmm3g2<<<SPMM_B + GB, 256, 0, stream>>>(row_start, ep, (const h16x4*)bufB,
                                               (h16x4*)bufA, flags3, bufB, out,
                                               users, pos_it, neg_it, u_a, p_a, n_a, indexp);
    // ---- hop-3 gather + fused hop-4 dot ----
    k_g3g4<<<GB, 256, 0, stream>>>(row_start, ep, (const h16x4*)bufA, out,
                                   users, pos_it, neg_it, u_a, p_a, n_a, indexp);
}

// Round 14
// 189.938 us; speedup vs baseline: 5.4626x; 1.0112x over previous
//
#include <hip/hip_runtime.h>
#include <stdint.h>

#define N_USER_C  50000
#define N_ITEM_C  100000
#define N_NODES_C 150000
#define EMB_C     64
#define NNZ_C     1200000
#define BATCH_C   4096

#define BKT_SHIFT 9                                   // 512 rows per bucket
#define BKT_ROWS  (1 << BKT_SHIFT)
#define NB        ((N_NODES_C + BKT_ROWS - 1) / BKT_ROWS)   // 293
#define CH        8192                                // edges per binning block
#define NBLK      ((NNZ_C + CH - 1) / CH)             // 147
#define N2        (NB * NBLK)                         // 43071
#define COL_MASK  0x3FFFF                             // 18 bits (N_NODES < 2^18)

#define SPMM_B    37500                               // 150000 waves / 4 per block
#define GB        3072                                // 786432 threads / 256
#define FB        3072                                // flag-seed blocks (12288 waves)
#define INIT_B    768                                 // 786432 threads / 1024
#define TH1_B     512                                 // tohalf stride blocks @1024

typedef _Float16 h16;
typedef _Float16 h16x4 __attribute__((ext_vector_type(4)));

// ---------------- shared device helpers ----------------
__device__ __forceinline__ void batch_row_a(int wid, int idx0,
                                            const int* __restrict__ users,
                                            const int* __restrict__ pos,
                                            const int* __restrict__ neg,
                                            const int* __restrict__ ua,
                                            const int* __restrict__ pa,
                                            const int* __restrict__ na,
                                            int& row, int& a) {
    int s = wid >> 12;
    int j = wid & (BATCH_C - 1);
    if (s == 0)      { row = users[j] + (idx0 ? N_USER_C : 0); a = ua[j]; }
    else if (s == 1) { row = pos[j]   + (idx0 ? 0 : N_USER_C); a = pa[j]; }
    else             { row = neg[j]   + (idx0 ? 0 : N_USER_C); a = na[j]; }
}

// ---------------- pass A (fused): histogram + flag zero  ∥  hop-0 init  ∥  tohalf ----------------
__global__ __launch_bounds__(1024) void k_bin_count(const float* __restrict__ du,
                                                    const int* __restrict__ rows,
                                                    int* __restrict__ cnt2,
                                                    int* __restrict__ flagz,
                                                    const float* __restrict__ ue,
                                                    const float* __restrict__ ie,
                                                    h16x4* __restrict__ dst,
                                                    float* __restrict__ out,
                                                    const int* __restrict__ users,
                                                    const int* __restrict__ pos,
                                                    const int* __restrict__ neg,
                                                    const int* __restrict__ ua,
                                                    const int* __restrict__ pa,
                                                    const int* __restrict__ na,
                                                    const int* __restrict__ indexp) {
    __shared__ int bk[NB];
    int t = threadIdx.x, blk = blockIdx.x;
    if (blk < NBLK) {                                  // edge histogram + flag zero
        for (int i = blk * 1024 + t; i < 2 * N_NODES_C; i += NBLK * 1024) flagz[i] = 0;
        for (int i = t; i < NB; i += 1024) bk[i] = 0;
        __syncthreads();
        int base = blk * CH;
        for (int i = 0; i < CH; i += 1024) {
            int e = base + i + t;
            if (e < NNZ_C && floorf(0.9f + du[e]) != 0.0f)
                atomicAdd(&bk[rows[e] >> BKT_SHIFT], 1);
        }
        __syncthreads();
        for (int i = t; i < NB; i += 1024) cnt2[i * NBLK + blk] = bk[i];
    } else if (blk < NBLK + INIT_B) {                  // pre-scaled hop-0 init
        int g = (blk - NBLK) * 1024 + t;               // < 786432 exactly
        int d = g & 63;
        int b = g >> 6;
        int row, a;
        batch_row_a(b, indexp[0], users, pos, neg, ua, pa, na, row, a);
        const float* sp = (row < N_USER_C) ? (ue + (int64_t)row * EMB_C)
                                           : (ie + (int64_t)(row - N_USER_C) * EMB_C);
        out[g] = sp[d] / (float)(a + 1);
    } else {                                           // f32 tables -> fp16 ego0
        const int totalU = N_USER_C * EMB_C / 4;
        const int total  = N_NODES_C * EMB_C / 4;
        const int stride = TH1_B * 1024;
        const float4* uev = (const float4*)ue;
        const float4* iev = (const float4*)ie;
        for (int i = (blk - NBLK - INIT_B) * 1024 + t; i < total; i += stride) {
            float4 v = (i < totalU) ? uev[i] : iev[i - totalU];
            h16x4 h;
            h[0] = (h16)v.x; h[1] = (h16)v.y; h[2] = (h16)v.z; h[3] = (h16)v.w;
            dst[i] = h;
        }
    }
}

// ---------------- pass B1: bucket totals + scan of 293 (round-10 proven) ----------------
__global__ __launch_bounds__(512) void k_bbase(const int* __restrict__ cnt2,
                                               int* __restrict__ bbase,
                                               int* __restrict__ base2,
                                               int* __restrict__ row_start) {
    __shared__ int sh[512];
    int t = threadIdx.x;
    int s = 0;
    if (t < NB) {
        const int* p = cnt2 + t * NBLK;
        for (int i = 0; i < NBLK; ++i) s += p[i];
    }
    sh[t] = s;
    __syncthreads();
    for (int off = 1; off < 512; off <<= 1) {
        int v = (t >= off) ? sh[t - off] : 0;
        __syncthreads();
        sh[t] += v;
        __syncthreads();
    }
    if (t < NB) bbase[t] = sh[t] - s;                  // exclusive bucket prefix
    if (t == 511) {
        base2[N2] = sh[511];                           // total kept edges
        row_start[N_NODES_C] = sh[511];                // CSR sentinel
    }
}

// ---------------- pass B2: per-bucket scan of 147 block counts ----------------
__global__ __launch_bounds__(256) void k_bscan(const int* __restrict__ cnt2,
                                               const int* __restrict__ bbase,
                                               int* __restrict__ base2) {
    __shared__ int sh[256];
    int t = threadIdx.x, i = blockIdx.x;
    int v0 = (t < NBLK) ? cnt2[i * NBLK + t] : 0;
    sh[t] = v0;
    __syncthreads();
    for (int off = 1; off < 256; off <<= 1) {
        int v = (t >= off) ? sh[t - off] : 0;
        __syncthreads();
        sh[t] += v;
        __syncthreads();
    }
    if (t < NBLK) base2[i * NBLK + t] = bbase[i] + sh[t] - v0;
}

// ---------------- pass C: bucket-sorted write of packed (rl|col, val) ----------------
__global__ __launch_bounds__(1024) void k_bin_write(const float* __restrict__ av,
                                                    const float* __restrict__ du,
                                                    const int* __restrict__ rows,
                                                    const int* __restrict__ cols,
                                                    const int* __restrict__ base2,
                                                    int2* __restrict__ ev) {
    __shared__ int cur[NB];
    int t = threadIdx.x, blk = blockIdx.x;
    for (int i = t; i < NB; i += 1024) cur[i] = base2[i * NBLK + blk];
    __syncthreads();
    int base = blk * CH;
    for (int i = 0; i < CH; i += 1024) {
        int e = base + i + t;
        if (e < NNZ_C) {
            float m = floorf(0.9f + du[e]);
            if (m != 0.0f) {
                float v = av[e] * m * (float)(1.0 / 0.9);
                int r = rows[e];
                int pos = atomicAdd(&cur[r >> BKT_SHIFT], 1);
                int2 p;
                p.x = ((r & (BKT_ROWS - 1)) << 18) | cols[e];   // rl:9 | col:18
                p.y = __float_as_int(v);
                ev[pos] = p;
            }
        }
    }
}

// ---------------- pass D: per-bucket exact row sort (LDS hist+scan+scatter) ----------------
__global__ __launch_bounds__(256) void k_bucket_sort(const int2* __restrict__ ev,
                                                     const int* __restrict__ base2,
                                                     int2* __restrict__ ep,
                                                     int* __restrict__ row_start) {
    __shared__ int rowcnt[BKT_ROWS];
    __shared__ int cursor[BKT_ROWS];
    __shared__ int tsum[256];
    int t = threadIdx.x, k = blockIdx.x;
    int rowBase = k << BKT_SHIFT;
    int bstart = base2[k * NBLK];
    int bend   = base2[(k + 1) * NBLK];               // k=NB-1 hits base2[N2]=total
    for (int i = t; i < BKT_ROWS; i += 256) rowcnt[i] = 0;
    __syncthreads();
    for (int e = bstart + t; e < bend; e += 256)
        atomicAdd(&rowcnt[((unsigned)ev[e].x) >> 18], 1);
    __syncthreads();
    int a = rowcnt[2 * t], b = rowcnt[2 * t + 1];
    tsum[t] = a + b;
    __syncthreads();
    for (int off = 1; off < 256; off <<= 1) {
        int v = (t >= off) ? tsum[t - off] : 0;
        __syncthreads();
        tsum[t] += v;
        __syncthreads();
    }
    int excl = tsum[t] - (a + b);
    cursor[2 * t]     = excl;
    cursor[2 * t + 1] = excl + a;
    int gr = rowBase + 2 * t;
    if (gr < N_NODES_C)     row_start[gr]     = bstart + excl;
    if (gr + 1 < N_NODES_C) row_start[gr + 1] = bstart + excl + a;
    __syncthreads();
    for (int e = bstart + t; e < bend; e += 256) {
        int2 p = ev[e];
        int rl = ((unsigned)p.x) >> 18;
        int slot = atomicAdd(&cursor[rl], 1);
        p.x &= COL_MASK;                               // strip rl -> clean col
        ep[bstart + slot] = p;
    }
}

__device__ __forceinline__ void spmm_row_body(int wid, int lane,
                                              const int* __restrict__ rs,
                                              const int2* __restrict__ ep,
                                              const h16x4* __restrict__ ego,
                                              h16x4* __restrict__ nxt,
                                              const int* __restrict__ flag) {
    if (wid >= N_NODES_C) return;
    if (flag && flag[wid] == 0) return;                // wave-uniform early exit
    int start = rs[wid];
    int end   = rs[wid + 1];
    int eo = lane >> 4;          // edge slot 0..3
    int l  = lane & 15;          // h16x4 index within the 128B row
    float4 acc = make_float4(0.f, 0.f, 0.f, 0.f);
    #pragma unroll 2
    for (int it = start + eo; it < end; it += 4) {
        int2 p = ep[it];
        float v = __int_as_float(p.y);
        h16x4 g = ego[(int64_t)p.x * 16 + l];          // 128B coalesced row gather
        acc.x += v * (float)g[0]; acc.y += v * (float)g[1];
        acc.z += v * (float)g[2]; acc.w += v * (float)g[3];
    }
    acc.x += __shfl_xor(acc.x, 16); acc.y += __shfl_xor(acc.y, 16);
    acc.z += __shfl_xor(acc.z, 16); acc.w += __shfl_xor(acc.w, 16);
    acc.x += __shfl_xor(acc.x, 32); acc.y += __shfl_xor(acc.y, 32);
    acc.z += __shfl_xor(acc.z, 32); acc.w += __shfl_xor(acc.w, 32);
    if (lane < 16) {
        h16x4 h;
        h[0] = (h16)acc.x; h[1] = (h16)acc.y; h[2] = (h16)acc.z; h[3] = (h16)acc.w;
        nxt[(int64_t)wid * 16 + l] = h;
    }
}

// gather-accumulate hop h, pre-scaled by 1/(a+1)
__device__ __forceinline__ void gather_body(const h16* __restrict__ src,
                                            float* __restrict__ out, int t, int hop,
                                            int idx0,
                                            const int* __restrict__ users,
                                            const int* __restrict__ pos,
                                            const int* __restrict__ neg,
                                            const int* __restrict__ ua,
                                            const int* __restrict__ pa,
                                            const int* __restrict__ na) {
    int d = t & 63;
    int b = t >> 6;
    int row, a;
    batch_row_a(b, idx0, users, pos, neg, ua, pa, na, row, a);
    if (hop <= a)
        out[t] += (float)src[(int64_t)row * EMB_C + d] / (float)(a + 1);
}

// ---------------- seed-only: need-flags (requires CSR) ----------------
__global__ __launch_bounds__(256) void k_seed(const int* __restrict__ rs,
                                              const int2* __restrict__ ep,
                                              int* __restrict__ flag3,
                                              int* __restrict__ flag2,
                                              const int* __restrict__ users,
                                              const int* __restrict__ pos,
                                              const int* __restrict__ neg,
                                              const int* __restrict__ ua,
                                              const int* __restrict__ pa,
                                              const int* __restrict__ na,
                                              const int* __restrict__ indexp) {
    int wid  = (blockIdx.x * 256 + threadIdx.x) >> 6;
    int lane = threadIdx.x & 63;
    if (wid >= 3 * BATCH_C) return;
    int row, a;
    batch_row_a(wid, indexp[0], users, pos, neg, ua, pa, na, row, a);
    if (a < 2) return;
    if (lane == 0) {
        flag2[row] = 1;                                // hop-2 gathered for a>=2
        if (a >= 3) flag3[row] = 1;                    // hop-3 gathered for a>=3
    }
    if (a == 4) {                                      // cols read by hop-4 dot
        int start = rs[row], end = rs[row + 1];
        for (int e = start + lane; e < end; e += 64)
            flag3[ep[e].x] = 1;                        // benign same-value races
    }
}

// ---------------- fused: hop-1 full SpMM  ∥  flags2 |= N(flags3) ----------------
__global__ __launch_bounds__(256) void k_spmm1f(const int* __restrict__ rs,
                                                const int2* __restrict__ ep,
                                                const h16x4* __restrict__ ego,
                                                h16x4* __restrict__ nxt,
                                                const int* __restrict__ flag3,
                                                int* __restrict__ flag2) {
    int lane = threadIdx.x & 63;
    if (blockIdx.x < SPMM_B) {                         // full hop-1 SpMM
        int wid = (blockIdx.x * 256 + threadIdx.x) >> 6;
        spmm_row_body(wid, lane, rs, ep, ego, nxt, (const int*)nullptr);
    } else {                                           // flags2 expansion (hidden)
        int wid = ((blockIdx.x - SPMM_B) * 256 + threadIdx.x) >> 6;
        if (wid >= N_NODES_C || flag3[wid] == 0) return;
        int start = rs[wid], end = rs[wid + 1];
        for (int e = start + lane; e < end; e += 64)
            flag2[ep[e].x] = 1;                        // benign same-value races
    }
}

// ---------------- fused: hop-2 SpMM (flags2)  ∥  hop-1 gather ----------------
__global__ __launch_bounds__(256) void k_spmm2g1(const int* __restrict__ rs,
                                                 const int2* __restrict__ ep,
                                                 const h16x4* __restrict__ ego,
                                                 h16x4* __restrict__ nxt,
                                                 const int* __restrict__ flag2,
                                                 const h16* __restrict__ gsrc,
                                                 float* __restrict__ out,
                                                 const int* __restrict__ users,
                                                 const int* __restrict__ pos,
                                                 const int* __restrict__ neg,
                                                 const int* __restrict__ ua,
                                                 const int* __restrict__ pa,
                                                 const int* __restrict__ na,
                                                 const int* __restrict__ indexp) {
    if (blockIdx.x < SPMM_B) {
        int wid  = (blockIdx.x * 256 + threadIdx.x) >> 6;
        int lane = threadIdx.x & 63;
        spmm_row_body(wid, lane, rs, ep, ego, nxt, flag2);
    } else {
        int t = (blockIdx.x - SPMM_B) * 256 + threadIdx.x;
        gather_body(gsrc, out, t, 1, indexp[0], users, pos, neg, ua, pa, na);
    }
}

// ---------------- fused: hop-3 SpMM (flags3)  ∥  hop-2 gather ----------------
__global__ __launch_bounds__(256) void k_spmm3g2(const int* __restrict__ rs,
                                                 const int2* __restrict__ ep,
                                                 const h16x4* __restrict__ ego,
                                                 h16x4* __restrict__ nxt,
                                                 const int* __restrict__ flag3,
                                                 const h16* __restrict__ gsrc,
                                                 float* __restrict__ out,
                                                 const int* __restrict__ users,
                                                 const int* __restrict__ pos,
                                                 const int* __restrict__ neg,
                                                 const int* __restrict__ ua,
                                                 const int* __restrict__ pa,
                                                 const int* __restrict__ na,
                                                 const int* __restrict__ indexp) {
    if (blockIdx.x < SPMM_B) {
        int wid  = (blockIdx.x * 256 + threadIdx.x) >> 6;
        int lane = threadIdx.x & 63;
        spmm_row_body(wid, lane, rs, ep, ego, nxt, flag3);
    } else {
        int t = (blockIdx.x - SPMM_B) * 256 + threadIdx.x;
        gather_body(gsrc, out, t, 2, indexp[0], users, pos, neg, ua, pa, na);
    }
}

// ---------------- fused epilogue: hop-3 gather + hop-4 dot, pre-scaled ----------------
__global__ __launch_bounds__(256) void k_g3g4(const int* __restrict__ rs,
                                              const int2* __restrict__ ep,
                                              const h16x4* __restrict__ ego,   // hop-3 values
                                              float* __restrict__ out,
                                              const int* __restrict__ users,
                                              const int* __restrict__ pos,
                                              const int* __restrict__ neg,
                                              const int* __restrict__ ua,
                                              const int* __restrict__ pa,
                                              const int* __restrict__ na,
                                              const int* __restrict__ indexp) {
    int gid  = blockIdx.x * 256 + threadIdx.x;
    int wid  = gid >> 6;                               // batch slot
    int lane = gid & 63;
    if (wid >= 3 * BATCH_C) return;
    int row, a;
    batch_row_a(wid, indexp[0], users, pos, neg, ua, pa, na, row, a);
    if (a < 3) return;                                 // wave-uniform
    float4 acc = make_float4(0.f, 0.f, 0.f, 0.f);
    if (a == 4) {                                      // E4 = (A*E3)[row]
        int start = rs[row], end = rs[row + 1];
        int eo = lane >> 4;
        int l  = lane & 15;
        for (int it = start + eo; it < end; it += 4) {
            int2 p = ep[it];
            float v = __int_as_float(p.y);
            h16x4 g = ego[(int64_t)p.x * 16 + l];
            acc.x += v * (float)g[0]; acc.y += v * (float)g[1];
            acc.z += v * (float)g[2]; acc.w += v * (float)g[3];
        }
        acc.x += __shfl_xor(acc.x, 16); acc.y += __shfl_xor(acc.y, 16);
        acc.z += __shfl_xor(acc.z, 16); acc.w += __shfl_xor(acc.w, 16);
        acc.x += __shfl_xor(acc.x, 32); acc.y += __shfl_xor(acc.y, 32);
        acc.z += __shfl_xor(acc.z, 32); acc.w += __shfl_xor(acc.w, 32);
    }
    if (lane < 16) {                                   // out += (E3 + E4) / (a+1)
        h16x4 g = ego[(int64_t)row * 16 + lane];
        float inv = 1.0f / (float)(a + 1);
        float4* o = (float4*)out + (int64_t)wid * 16 + lane;
        float4 cv = *o;
        cv.x += ((float)g[0] + acc.x) * inv;
        cv.y += ((float)g[1] + acc.y) * inv;
        cv.z += ((float)g[2] + acc.z) * inv;
        cv.w += ((float)g[3] + acc.w) * inv;
        *o = cv;
    }
}

extern "C" void kernel_launch(void* const* d_in, const int* in_sizes, int n_in,
                              void* d_out, int out_size, void* d_ws, size_t ws_size,
                              hipStream_t stream) {
    const float* user_emb = (const float*)d_in[0];
    const float* item_emb = (const float*)d_in[1];
    const float* adj_vals = (const float*)d_in[2];
    const float* drop_u   = (const float*)d_in[3];
    const int*   adj_rows = (const int*)d_in[4];
    const int*   adj_cols = (const int*)d_in[5];
    const int*   users    = (const int*)d_in[6];
    const int*   pos_it   = (const int*)d_in[7];
    const int*   neg_it   = (const int*)d_in[8];
    const int*   u_a      = (const int*)d_in[9];
    const int*   p_a      = (const int*)d_in[10];
    const int*   n_a      = (const int*)d_in[11];
    const int*   indexp   = (const int*)d_in[12];
    float* out = (float*)d_out;

    // workspace layout (~79 MB)
    const size_t egoElems = (size_t)N_NODES_C * EMB_C;       // 9.6M
    h16*   egoH0     = (h16*)d_ws;                           // 19.2 MB
    h16*   bufA      = egoH0 + egoElems;                     // 19.2 MB
    h16*   bufB      = bufA + egoElems;                      // 19.2 MB
    int2*  ep        = (int2*)(bufB + egoElems);             // 9.6 MB (final CSR)
    int2*  ev        = ep + NNZ_C;                           // 9.6 MB (build tmp)
    int*   row_start = (int*)(ev + NNZ_C);                   // 600 KB (+sentinel)
    int*   cnt2      = row_start + N_NODES_C + 1;            // ~172 KB
    int*   base2     = cnt2 + N2 + 1;                        // ~172 KB (+sentinel)
    int*   bbase     = base2 + N2 + 1;                       // ~1.2 KB
    int*   flags3    = bbase + NB + 1;                       // 600 KB
    int*   flags2    = flags3 + N_NODES_C;                   // 600 KB (contiguous)

    // ---- pass A: build histogram ∥ hop-0 init ∥ fp16 conversion (1 dispatch) ----
    k_bin_count<<<NBLK + INIT_B + TH1_B, 1024, 0, stream>>>(
        drop_u, adj_rows, cnt2, flags3,
        user_emb, item_emb, (h16x4*)egoH0, out,
        users, pos_it, neg_it, u_a, p_a, n_a, indexp);

    // ---- rest of CSR build ----
    k_bbase<<<1, 512, 0, stream>>>(cnt2, bbase, base2, row_start);
    k_bscan<<<NB, 256, 0, stream>>>(cnt2, bbase, base2);
    k_bin_write<<<NBLK, 1024, 0, stream>>>(adj_vals, drop_u, adj_rows, adj_cols,
                                           base2, ev);
    k_bucket_sort<<<NB, 256, 0, stream>>>(ev, base2, ep, row_start);

    // ---- need-flag seeding (requires CSR) ----
    k_seed<<<FB, 256, 0, stream>>>(row_start, ep, flags3, flags2,
                                   users, pos_it, neg_it, u_a, p_a, n_a, indexp);

    // ---- hop-1 full SpMM ∥ flags2 expansion (hidden under SpMM) ----
    k_spmm1f<<<SPMM_B + SPMM_B, 256, 0, stream>>>(row_start, ep, (const h16x4*)egoH0,
                                                  (h16x4*)bufA, flags3, flags2);
    // ---- hop-2 SpMM (flags2) ∥ hop-1 gather ----
    k_spmm2g1<<<SPMM_B + GB, 256, 0, stream>>>(row_start, ep, (const h16x4*)bufA,
                                               (h16x4*)bufB, flags2, bufA, out,
                                               users, pos_it, neg_it, u_a, p_a, n_a, indexp);
    // ---- hop-3 SpMM (flags3) ∥ hop-2 gather ----
    k_spmm3g2<<<SPMM_B + GB, 256, 0, stream>>>(row_start, ep, (const h16x4*)bufB,
                                               (h16x4*)bufA, flags3, bufB, out,
                                               users, pos_it, neg_it, u_a, p_a, n_a, indexp);
    // ---- hop-3 gather + fused hop-4 dot ----
    k_g3g4<<<GB, 256, 0, stream>>>(row_start, ep, (const h16x4*)bufA, out,
                                   users, pos_it, neg_it, u_a, p_a, n_a, indexp);
}

// Round 15
// 179.807 us; speedup vs baseline: 5.7704x; 1.0563x over previous
//
#include <hip/hip_runtime.h>
#include <stdint.h>

#define N_USER_C  50000
#define N_ITEM_C  100000
#define N_NODES_C 150000
#define EMB_C     64
#define NNZ_C     1200000
#define BATCH_C   4096

#define BKT_SHIFT 9                                   // 512 rows per bucket
#define BKT_ROWS  (1 << BKT_SHIFT)
#define NB        ((N_NODES_C + BKT_ROWS - 1) / BKT_ROWS)   // 293
#define CH        8192                                // edges per binning block
#define NBLK      ((NNZ_C + CH - 1) / CH)             // 147
#define N2        (NB * NBLK)                         // 43071
#define COL_MASK  0x3FFFF                             // 18 bits (N_NODES < 2^18)

#define SPMM_B    37500                               // 150000 waves / 4 per block
#define GB        3072                                // 786432 threads / 256
#define SEED_B    3072                                // seed tail blocks (12288 waves)
#define INIT_B    768                                 // 786432 threads / 1024
#define TH1_B     512                                 // tohalf stride blocks @1024

typedef _Float16 h16;
typedef _Float16 h16x4 __attribute__((ext_vector_type(4)));

// ---------------- shared device helpers ----------------
__device__ __forceinline__ void batch_row_a(int wid, int idx0,
                                            const int* __restrict__ users,
                                            const int* __restrict__ pos,
                                            const int* __restrict__ neg,
                                            const int* __restrict__ ua,
                                            const int* __restrict__ pa,
                                            const int* __restrict__ na,
                                            int& row, int& a) {
    int s = wid >> 12;
    int j = wid & (BATCH_C - 1);
    if (s == 0)      { row = users[j] + (idx0 ? N_USER_C : 0); a = ua[j]; }
    else if (s == 1) { row = pos[j]   + (idx0 ? 0 : N_USER_C); a = pa[j]; }
    else             { row = neg[j]   + (idx0 ? 0 : N_USER_C); a = na[j]; }
}

// ---------------- pass A (fused): histogram + flags3 zero  ∥  hop-0 init  ∥  tohalf ----------------
__global__ __launch_bounds__(1024) void k_bin_count(const float* __restrict__ du,
                                                    const int* __restrict__ rows,
                                                    int* __restrict__ cnt2,
                                                    int* __restrict__ flagz,
                                                    const float* __restrict__ ue,
                                                    const float* __restrict__ ie,
                                                    h16x4* __restrict__ dst,
                                                    float* __restrict__ out,
                                                    const int* __restrict__ users,
                                                    const int* __restrict__ pos,
                                                    const int* __restrict__ neg,
                                                    const int* __restrict__ ua,
                                                    const int* __restrict__ pa,
                                                    const int* __restrict__ na,
                                                    const int* __restrict__ indexp) {
    __shared__ int bk[NB];
    int t = threadIdx.x, blk = blockIdx.x;
    if (blk < NBLK) {                                  // edge histogram + flags3 zero
        for (int i = blk * 1024 + t; i < N_NODES_C; i += NBLK * 1024) flagz[i] = 0;
        for (int i = t; i < NB; i += 1024) bk[i] = 0;
        __syncthreads();
        int base = blk * CH;
        for (int i = 0; i < CH; i += 1024) {
            int e = base + i + t;
            if (e < NNZ_C && floorf(0.9f + du[e]) != 0.0f)
                atomicAdd(&bk[rows[e] >> BKT_SHIFT], 1);
        }
        __syncthreads();
        for (int i = t; i < NB; i += 1024) cnt2[i * NBLK + blk] = bk[i];
    } else if (blk < NBLK + INIT_B) {                  // pre-scaled hop-0 init
        int g = (blk - NBLK) * 1024 + t;               // < 786432 exactly
        int d = g & 63;
        int b = g >> 6;
        int row, a;
        batch_row_a(b, indexp[0], users, pos, neg, ua, pa, na, row, a);
        const float* sp = (row < N_USER_C) ? (ue + (int64_t)row * EMB_C)
                                           : (ie + (int64_t)(row - N_USER_C) * EMB_C);
        out[g] = sp[d] / (float)(a + 1);
    } else {                                           // f32 tables -> fp16 ego0
        const int totalU = N_USER_C * EMB_C / 4;
        const int total  = N_NODES_C * EMB_C / 4;
        const int stride = TH1_B * 1024;
        const float4* uev = (const float4*)ue;
        const float4* iev = (const float4*)ie;
        for (int i = (blk - NBLK - INIT_B) * 1024 + t; i < total; i += stride) {
            float4 v = (i < totalU) ? uev[i] : iev[i - totalU];
            h16x4 h;
            h[0] = (h16)v.x; h[1] = (h16)v.y; h[2] = (h16)v.z; h[3] = (h16)v.w;
            dst[i] = h;
        }
    }
}

// ---------------- pass B1: bucket totals + scan of 293 ----------------
__global__ __launch_bounds__(512) void k_bbase(const int* __restrict__ cnt2,
                                               int* __restrict__ bbase,
                                               int* __restrict__ base2,
                                               int* __restrict__ row_start) {
    __shared__ int sh[512];
    int t = threadIdx.x;
    int s = 0;
    if (t < NB) {
        const int* p = cnt2 + t * NBLK;
        for (int i = 0; i < NBLK; ++i) s += p[i];
    }
    sh[t] = s;
    __syncthreads();
    for (int off = 1; off < 512; off <<= 1) {
        int v = (t >= off) ? sh[t - off] : 0;
        __syncthreads();
        sh[t] += v;
        __syncthreads();
    }
    if (t < NB) bbase[t] = sh[t] - s;                  // exclusive bucket prefix
    if (t == 511) {
        base2[N2] = sh[511];                           // total kept edges
        row_start[N_NODES_C] = sh[511];                // CSR sentinel
    }
}

// ---------------- pass B2: per-bucket scan of 147 block counts ----------------
__global__ __launch_bounds__(256) void k_bscan(const int* __restrict__ cnt2,
                                               const int* __restrict__ bbase,
                                               int* __restrict__ base2) {
    __shared__ int sh[256];
    int t = threadIdx.x, i = blockIdx.x;
    int v0 = (t < NBLK) ? cnt2[i * NBLK + t] : 0;
    sh[t] = v0;
    __syncthreads();
    for (int off = 1; off < 256; off <<= 1) {
        int v = (t >= off) ? sh[t - off] : 0;
        __syncthreads();
        sh[t] += v;
        __syncthreads();
    }
    if (t < NBLK) base2[i * NBLK + t] = bbase[i] + sh[t] - v0;
}

// ---------------- pass C: bucket-sorted write of packed (rl|col, val) ----------------
__global__ __launch_bounds__(1024) void k_bin_write(const float* __restrict__ av,
                                                    const float* __restrict__ du,
                                                    const int* __restrict__ rows,
                                                    const int* __restrict__ cols,
                                                    const int* __restrict__ base2,
                                                    int2* __restrict__ ev) {
    __shared__ int cur[NB];
    int t = threadIdx.x, blk = blockIdx.x;
    for (int i = t; i < NB; i += 1024) cur[i] = base2[i * NBLK + blk];
    __syncthreads();
    int base = blk * CH;
    for (int i = 0; i < CH; i += 1024) {
        int e = base + i + t;
        if (e < NNZ_C) {
            float m = floorf(0.9f + du[e]);
            if (m != 0.0f) {
                float v = av[e] * m * (float)(1.0 / 0.9);
                int r = rows[e];
                int pos = atomicAdd(&cur[r >> BKT_SHIFT], 1);
                int2 p;
                p.x = ((r & (BKT_ROWS - 1)) << 18) | cols[e];   // rl:9 | col:18
                p.y = __float_as_int(v);
                ev[pos] = p;
            }
        }
    }
}

// ---------------- pass D: per-bucket exact row sort (LDS hist+scan+scatter) ----------------
__global__ __launch_bounds__(256) void k_bucket_sort(const int2* __restrict__ ev,
                                                     const int* __restrict__ base2,
                                                     int2* __restrict__ ep,
                                                     int* __restrict__ row_start) {
    __shared__ int rowcnt[BKT_ROWS];
    __shared__ int cursor[BKT_ROWS];
    __shared__ int tsum[256];
    int t = threadIdx.x, k = blockIdx.x;
    int rowBase = k << BKT_SHIFT;
    int bstart = base2[k * NBLK];
    int bend   = base2[(k + 1) * NBLK];               // k=NB-1 hits base2[N2]=total
    for (int i = t; i < BKT_ROWS; i += 256) rowcnt[i] = 0;
    __syncthreads();
    for (int e = bstart + t; e < bend; e += 256)
        atomicAdd(&rowcnt[((unsigned)ev[e].x) >> 18], 1);
    __syncthreads();
    int a = rowcnt[2 * t], b = rowcnt[2 * t + 1];
    tsum[t] = a + b;
    __syncthreads();
    for (int off = 1; off < 256; off <<= 1) {
        int v = (t >= off) ? tsum[t - off] : 0;
        __syncthreads();
        tsum[t] += v;
        __syncthreads();
    }
    int excl = tsum[t] - (a + b);
    cursor[2 * t]     = excl;
    cursor[2 * t + 1] = excl + a;
    int gr = rowBase + 2 * t;
    if (gr < N_NODES_C)     row_start[gr]     = bstart + excl;
    if (gr + 1 < N_NODES_C) row_start[gr + 1] = bstart + excl + a;
    __syncthreads();
    for (int e = bstart + t; e < bend; e += 256) {
        int2 p = ev[e];
        int rl = ((unsigned)p.x) >> 18;
        int slot = atomicAdd(&cursor[rl], 1);
        p.x &= COL_MASK;                               // strip rl -> clean col
        ep[bstart + slot] = p;
    }
}

__device__ __forceinline__ void spmm_row_body(int wid, int lane,
                                              const int* __restrict__ rs,
                                              const int2* __restrict__ ep,
                                              const h16x4* __restrict__ ego,
                                              h16x4* __restrict__ nxt,
                                              const int* __restrict__ flag) {
    if (wid >= N_NODES_C) return;
    if (flag && flag[wid] == 0) return;                // wave-uniform early exit
    int start = rs[wid];
    int end   = rs[wid + 1];
    int eo = lane >> 4;          // edge slot 0..3
    int l  = lane & 15;          // h16x4 index within the 128B row
    float4 acc = make_float4(0.f, 0.f, 0.f, 0.f);
    #pragma unroll 2
    for (int it = start + eo; it < end; it += 4) {
        int2 p = ep[it];
        float v = __int_as_float(p.y);
        h16x4 g = ego[(int64_t)p.x * 16 + l];          // 128B coalesced row gather
        acc.x += v * (float)g[0]; acc.y += v * (float)g[1];
        acc.z += v * (float)g[2]; acc.w += v * (float)g[3];
    }
    acc.x += __shfl_xor(acc.x, 16); acc.y += __shfl_xor(acc.y, 16);
    acc.z += __shfl_xor(acc.z, 16); acc.w += __shfl_xor(acc.w, 16);
    acc.x += __shfl_xor(acc.x, 32); acc.y += __shfl_xor(acc.y, 32);
    acc.z += __shfl_xor(acc.z, 32); acc.w += __shfl_xor(acc.w, 32);
    if (lane < 16) {
        h16x4 h;
        h[0] = (h16)acc.x; h[1] = (h16)acc.y; h[2] = (h16)acc.z; h[3] = (h16)acc.w;
        nxt[(int64_t)wid * 16 + l] = h;
    }
}

// gather-accumulate hop h, pre-scaled by 1/(a+1)
__device__ __forceinline__ void gather_body(const h16* __restrict__ src,
                                            float* __restrict__ out, int t, int hop,
                                            int idx0,
                                            const int* __restrict__ users,
                                            const int* __restrict__ pos,
                                            const int* __restrict__ neg,
                                            const int* __restrict__ ua,
                                            const int* __restrict__ pa,
                                            const int* __restrict__ na) {
    int d = t & 63;
    int b = t >> 6;
    int row, a;
    batch_row_a(b, idx0, users, pos, neg, ua, pa, na, row, a);
    if (hop <= a)
        out[t] += (float)src[(int64_t)row * EMB_C + d] / (float)(a + 1);
}

// ---------------- fused: hop-1 full SpMM  ∥  flags3 seeding (tiny tail) ----------------
__global__ __launch_bounds__(256) void k_spmm1s(const int* __restrict__ rs,
                                                const int2* __restrict__ ep,
                                                const h16x4* __restrict__ ego,
                                                h16x4* __restrict__ nxt,
                                                int* __restrict__ flag3,
                                                const int* __restrict__ users,
                                                const int* __restrict__ pos,
                                                const int* __restrict__ neg,
                                                const int* __restrict__ ua,
                                                const int* __restrict__ pa,
                                                const int* __restrict__ na,
                                                const int* __restrict__ indexp) {
    int lane = threadIdx.x & 63;
    if (blockIdx.x < SPMM_B) {                         // full hop-1 SpMM
        int wid = (blockIdx.x * 256 + threadIdx.x) >> 6;
        spmm_row_body(wid, lane, rs, ep, ego, nxt, (const int*)nullptr);
    } else {                                           // flags3 seeding (hidden, tiny)
        int wid = ((blockIdx.x - SPMM_B) * 256 + threadIdx.x) >> 6;
        if (wid >= 3 * BATCH_C) return;
        int row, a;
        batch_row_a(wid, indexp[0], users, pos, neg, ua, pa, na, row, a);
        if (a < 3) return;
        if (lane == 0) flag3[row] = 1;                 // hop-3 gathered for a>=3
        if (a == 4) {                                  // cols read by hop-4 dot
            int start = rs[row], end = rs[row + 1];
            for (int e = start + lane; e < end; e += 64)
                flag3[ep[e].x] = 1;                    // benign same-value races
        }
    }
}

// ---------------- fused: hop-2 full SpMM  ∥  hop-1 gather ----------------
__global__ __launch_bounds__(256) void k_spmm2g1(const int* __restrict__ rs,
                                                 const int2* __restrict__ ep,
                                                 const h16x4* __restrict__ ego,
                                                 h16x4* __restrict__ nxt,
                                                 const h16* __restrict__ gsrc,
                                                 float* __restrict__ out,
                                                 const int* __restrict__ users,
                                                 const int* __restrict__ pos,
                                                 const int* __restrict__ neg,
                                                 const int* __restrict__ ua,
                                                 const int* __restrict__ pa,
                                                 const int* __restrict__ na,
                                                 const int* __restrict__ indexp) {
    if (blockIdx.x < SPMM_B) {
        int wid  = (blockIdx.x * 256 + threadIdx.x) >> 6;
        int lane = threadIdx.x & 63;
        spmm_row_body(wid, lane, rs, ep, ego, nxt, (const int*)nullptr);
    } else {
        int t = (blockIdx.x - SPMM_B) * 256 + threadIdx.x;
        gather_body(gsrc, out, t, 1, indexp[0], users, pos, neg, ua, pa, na);
    }
}

// ---------------- fused: hop-3 SpMM (flags3)  ∥  hop-2 gather ----------------
__global__ __launch_bounds__(256) void k_spmm3g2(const int* __restrict__ rs,
                                                 const int2* __restrict__ ep,
                                                 const h16x4* __restrict__ ego,
                                                 h16x4* __restrict__ nxt,
                                                 const int* __restrict__ flag3,
                                                 const h16* __restrict__ gsrc,
                                                 float* __restrict__ out,
                                                 const int* __restrict__ users,
                                                 const int* __restrict__ pos,
                                                 const int* __restrict__ neg,
                                                 const int* __restrict__ ua,
                                                 const int* __restrict__ pa,
                                                 const int* __restrict__ na,
                                                 const int* __restrict__ indexp) {
    if (blockIdx.x < SPMM_B) {
        int wid  = (blockIdx.x * 256 + threadIdx.x) >> 6;
        int lane = threadIdx.x & 63;
        spmm_row_body(wid, lane, rs, ep, ego, nxt, flag3);
    } else {
        int t = (blockIdx.x - SPMM_B) * 256 + threadIdx.x;
        gather_body(gsrc, out, t, 2, indexp[0], users, pos, neg, ua, pa, na);
    }
}

// ---------------- fused epilogue: hop-3 gather + hop-4 dot, pre-scaled ----------------
__global__ __launch_bounds__(256) void k_g3g4(const int* __restrict__ rs,
                                              const int2* __restrict__ ep,
                                              const h16x4* __restrict__ ego,   // hop-3 values
                                              float* __restrict__ out,
                                              const int* __restrict__ users,
                                              const int* __restrict__ pos,
                                              const int* __restrict__ neg,
                                              const int* __restrict__ ua,
                                              const int* __restrict__ pa,
                                              const int* __restrict__ na,
                                              const int* __restrict__ indexp) {
    int gid  = blockIdx.x * 256 + threadIdx.x;
    int wid  = gid >> 6;                               // batch slot
    int lane = gid & 63;
    if (wid >= 3 * BATCH_C) return;
    int row, a;
    batch_row_a(wid, indexp[0], users, pos, neg, ua, pa, na, row, a);
    if (a < 3) return;                                 // wave-uniform
    float4 acc = make_float4(0.f, 0.f, 0.f, 0.f);
    if (a == 4) {                                      // E4 = (A*E3)[row]
        int start = rs[row], end = rs[row + 1];
        int eo = lane >> 4;
        int l  = lane & 15;
        for (int it = start + eo; it < end; it += 4) {
            int2 p = ep[it];
            float v = __int_as_float(p.y);
            h16x4 g = ego[(int64_t)p.x * 16 + l];
            acc.x += v * (float)g[0]; acc.y += v * (float)g[1];
            acc.z += v * (float)g[2]; acc.w += v * (float)g[3];
        }
        acc.x += __shfl_xor(acc.x, 16); acc.y += __shfl_xor(acc.y, 16);
        acc.z += __shfl_xor(acc.z, 16); acc.w += __shfl_xor(acc.w, 16);
        acc.x += __shfl_xor(acc.x, 32); acc.y += __shfl_xor(acc.y, 32);
        acc.z += __shfl_xor(acc.z, 32); acc.w += __shfl_xor(acc.w, 32);
    }
    if (lane < 16) {                                   // out += (E3 + E4) / (a+1)
        h16x4 g = ego[(int64_t)row * 16 + lane];
        float inv = 1.0f / (float)(a + 1);
        float4* o = (float4*)out + (int64_t)wid * 16 + lane;
        float4 cv = *o;
        cv.x += ((float)g[0] + acc.x) * inv;
        cv.y += ((float)g[1] + acc.y) * inv;
        cv.z += ((float)g[2] + acc.z) * inv;
        cv.w += ((float)g[3] + acc.w) * inv;
        *o = cv;
    }
}

extern "C" void kernel_launch(void* const* d_in, const int* in_sizes, int n_in,
                              void* d_out, int out_size, void* d_ws, size_t ws_size,
                              hipStream_t stream) {
    const float* user_emb = (const float*)d_in[0];
    const float* item_emb = (const float*)d_in[1];
    const float* adj_vals = (const float*)d_in[2];
    const float* drop_u   = (const float*)d_in[3];
    const int*   adj_rows = (const int*)d_in[4];
    const int*   adj_cols = (const int*)d_in[5];
    const int*   users    = (const int*)d_in[6];
    const int*   pos_it   = (const int*)d_in[7];
    const int*   neg_it   = (const int*)d_in[8];
    const int*   u_a      = (const int*)d_in[9];
    const int*   p_a      = (const int*)d_in[10];
    const int*   n_a      = (const int*)d_in[11];
    const int*   indexp   = (const int*)d_in[12];
    float* out = (float*)d_out;

    // workspace layout (~78 MB)
    const size_t egoElems = (size_t)N_NODES_C * EMB_C;       // 9.6M
    h16*   egoH0     = (h16*)d_ws;                           // 19.2 MB
    h16*   bufA      = egoH0 + egoElems;                     // 19.2 MB
    h16*   bufB      = bufA + egoElems;                      // 19.2 MB
    int2*  ep        = (int2*)(bufB + egoElems);             // 9.6 MB (final CSR)
    int2*  ev        = ep + NNZ_C;                           // 9.6 MB (build tmp)
    int*   row_start = (int*)(ev + NNZ_C);                   // 600 KB (+sentinel)
    int*   cnt2      = row_start + N_NODES_C + 1;            // ~172 KB
    int*   base2     = cnt2 + N2 + 1;                        // ~172 KB (+sentinel)
    int*   bbase     = base2 + N2 + 1;                       // ~1.2 KB
    int*   flags3    = bbase + NB + 1;                       // 600 KB

    // ---- pass A: build histogram ∥ hop-0 init ∥ fp16 conversion (1 dispatch) ----
    k_bin_count<<<NBLK + INIT_B + TH1_B, 1024, 0, stream>>>(
        drop_u, adj_rows, cnt2, flags3,
        user_emb, item_emb, (h16x4*)egoH0, out,
        users, pos_it, neg_it, u_a, p_a, n_a, indexp);

    // ---- rest of CSR build ----
    k_bbase<<<1, 512, 0, stream>>>(cnt2, bbase, base2, row_start);
    k_bscan<<<NB, 256, 0, stream>>>(cnt2, bbase, base2);
    k_bin_write<<<NBLK, 1024, 0, stream>>>(adj_vals, drop_u, adj_rows, adj_cols,
                                           base2, ev);
    k_bucket_sort<<<NB, 256, 0, stream>>>(ev, base2, ep, row_start);

    // ---- hop-1 full SpMM ∥ flags3 seeding (hidden) ----
    k_spmm1s<<<SPMM_B + SEED_B, 256, 0, stream>>>(row_start, ep, (const h16x4*)egoH0,
                                                  (h16x4*)bufA, flags3,
                                                  users, pos_it, neg_it, u_a, p_a, n_a, indexp);
    // ---- hop-2 full SpMM ∥ hop-1 gather ----
    k_spmm2g1<<<SPMM_B + GB, 256, 0, stream>>>(row_start, ep, (const h16x4*)bufA,
                                               (h16x4*)bufB, bufA, out,
                                               users, pos_it, neg_it, u_a, p_a, n_a, indexp);
    // ---- hop-3 SpMM (flags3) ∥ hop-2 gather ----
    k_spmm3g2<<<SPMM_B + GB, 256, 0, stream>>>(row_start, ep, (const h16x4*)bufB,
                                               (h16x4*)bufA, flags3, bufB, out,
                                               users, pos_it, neg_it, u_a, p_a, n_a, indexp);
    // ---- hop-3 gather + fused hop-4 dot ----
    k_g3g4<<<GB, 256, 0, stream>>>(row_start, ep, (const h16x4*)bufA, out,
                                   users, pos_it, neg_it, u_a, p_a, n_a, indexp);
}